// Round 1
// baseline (934.386 us; speedup 1.0000x reference)
//
#include <hip/hip_runtime.h>
#include <hip/hip_bf16.h>
#include <math.h>

// ---------------- problem constants ----------------
#define D_MODEL   1024
#define K_TOT     32
#define KQ_DIM    4
#define N_ANCHOR  4
#define N_DECAY   28
#define M_DIM     8
#define KS        4
#define H_DIM     32
#define N_REP     8
#define DIM_K     1024
#define DIM_DECAY 32
#define DIM_MEM   (DIM_K + DIM_DECAY)   // 1056
#define DIM_Q     2048
#define TOTAL_DIM 3104
#define B_SZ      2
#define L_SEQ     2048
#define BL_TOT    (B_SZ * L_SEQ)        // 4096

#define NCHUNK    32
#define CHUNK_L   (L_SEQ / NCHUNK)      // 64

// ---------------- fp32 tiled GEMM: C[M,N] = A[M,K] * B[K,N] ----------------
// BM=BN=64, BK=16, 256 threads, 4x4 microtile per thread.
__global__ __launch_bounds__(256) void gemm_f32(const float* __restrict__ A,
                                                const float* __restrict__ Bm,
                                                float* __restrict__ C,
                                                int Mdim, int Ndim, int Kdim) {
    const int BM = 64, BN = 64, BK = 16;
    __shared__ float As[BK][BM + 1];
    __shared__ float Bs[BK][BN + 1];

    const int tid = threadIdx.x;
    const int tx = tid & 15;        // N direction (16 threads * 4 cols)
    const int ty = tid >> 4;        // M direction (16 threads * 4 rows)
    const int row0 = blockIdx.y * BM;
    const int col0 = blockIdx.x * BN;

    float acc[4][4] = {};

    for (int k0 = 0; k0 < Kdim; k0 += BK) {
        // load A tile: 64 rows x 16 cols (1024 elems, 4 per thread)
#pragma unroll
        for (int i = 0; i < 4; i++) {
            int e = tid + 256 * i;
            int r = e >> 4;          // 0..63
            int c = e & 15;          // 0..15
            int gr = row0 + r;
            float v = 0.f;
            if (gr < Mdim) v = A[(size_t)gr * Kdim + k0 + c];
            As[c][r] = v;
        }
        // load B tile: 16 rows x 64 cols
#pragma unroll
        for (int i = 0; i < 4; i++) {
            int e = tid + 256 * i;
            int r = e >> 6;          // 0..15
            int c = e & 63;          // 0..63
            int gc = col0 + c;
            float v = 0.f;
            if (gc < Ndim) v = Bm[(size_t)(k0 + r) * Ndim + gc];
            Bs[r][c] = v;
        }
        __syncthreads();

#pragma unroll
        for (int kk = 0; kk < BK; kk++) {
            float a[4], b[4];
#pragma unroll
            for (int i = 0; i < 4; i++) a[i] = As[kk][ty * 4 + i];
#pragma unroll
            for (int j = 0; j < 4; j++) b[j] = Bs[kk][tx * 4 + j];
#pragma unroll
            for (int i = 0; i < 4; i++)
#pragma unroll
                for (int j = 0; j < 4; j++) acc[i][j] += a[i] * b[j];
        }
        __syncthreads();
    }

#pragma unroll
    for (int i = 0; i < 4; i++) {
        int gr = row0 + ty * 4 + i;
        if (gr >= Mdim) continue;
#pragma unroll
        for (int j = 0; j < 4; j++) {
            int gc = col0 + tx * 4 + j;
            if (gc < Ndim) C[(size_t)gr * Ndim + gc] = acc[i][j];
        }
    }
}

// ---------------- depthwise causal conv + gate weights ----------------
// one block per (b,l); threads loop channels 0..1055
__global__ __launch_bounds__(256) void conv_pw(const float* __restrict__ z,
                                               const float* __restrict__ conv_k,
                                               const float* __restrict__ score_scale,
                                               const float* __restrict__ decay_slopes,
                                               const float* __restrict__ anchor_slopes,
                                               float* __restrict__ k_val,
                                               float* __restrict__ p_w) {
    const int bl = blockIdx.x;          // b*L + l
    const int l = bl & (L_SEQ - 1);
    const int b = bl >> 11;             // /2048

    for (int c = threadIdx.x; c < DIM_MEM; c += blockDim.x) {
        float acc = 0.f;
#pragma unroll
        for (int s = 0; s < KS; s++) {
            int t = l - (KS - 1) + s;
            if (t >= 0)
                acc += conv_k[s * DIM_MEM + c] *
                       z[((size_t)b * L_SEQ + t) * TOTAL_DIM + c];
        }
        if (c < DIM_K) {
            k_val[(size_t)bl * DIM_K + c] = acc;
        } else {
            int k = c - DIM_K;
            float lp = fminf(fmaxf(score_scale[k] * acc, -20.f), 20.f);
            float lt;
            if (k < N_DECAY) {
                float sd = log1pf(expf(decay_slopes[k]));
                lt = -sd * (float)(L_SEQ - 1 - l);
            } else {
                float sa = log1pf(expf(anchor_slopes[k - N_DECAY]));
                lt = -sa * (float)l;
            }
            p_w[(size_t)bl * K_TOT + k] = expf(lp + lt);
        }
    }
}

// ---------------- phase 1: per-chunk totals ----------------
// blockIdx.x = (b*K + k)*NCHUNK + c ; thread t -> (h = t>>3, m = t&7)
__global__ __launch_bounds__(256) void chunk_sums(const float* __restrict__ k_val,
                                                  const float* __restrict__ p_w,
                                                  const float* __restrict__ theta,
                                                  float* __restrict__ csum,
                                                  float* __restrict__ cden) {
    const int idx = blockIdx.x;
    const int c = idx & (NCHUNK - 1);
    const int bk = idx / NCHUNK;
    const int k = bk & (K_TOT - 1);
    const int b = bk / K_TOT;
    const int t = threadIdx.x;
    const int h = t >> 3;
    const int m = t & 7;

    const float th = theta[(k * H_DIM + h) * M_DIM + m];
    float sre = 0.f, sim = 0.f, sden = 0.f;
    const int l0 = c * CHUNK_L;
    for (int i = 0; i < CHUNK_L; i++) {
        size_t bl = (size_t)b * L_SEQ + (l0 + i);
        float p = p_w[bl * K_TOT + k];
        float kv = k_val[bl * DIM_K + k * H_DIM + h];
        float s, cs;
        sincosf(kv * th, &s, &cs);
        sre += p * cs;
        sim += p * s;
        sden += p;
    }
    size_t base = ((size_t)idx * 256 + t) * 2;
    csum[base] = sre;
    csum[base + 1] = sim;
    if (t == 0) cden[idx] = sden;
}

// ---------------- phase 2: exclusive prefix over chunks ----------------
// blockIdx.x = b*K + k
__global__ __launch_bounds__(256) void chunk_prefix(float* __restrict__ csum,
                                                    float* __restrict__ cden) {
    const int bk = blockIdx.x;
    const int t = threadIdx.x;
    float run_re = 0.f, run_im = 0.f;
    for (int c = 0; c < NCHUNK; c++) {
        size_t base = (((size_t)bk * NCHUNK + c) * 256 + t) * 2;
        float re = csum[base], im = csum[base + 1];
        csum[base] = run_re;
        csum[base + 1] = run_im;
        run_re += re;
        run_im += im;
    }
    if (t == 0) {
        float run = 0.f;
        for (int c = 0; c < NCHUNK; c++) {
            float v = cden[bk * NCHUNK + c];
            cden[bk * NCHUNK + c] = run;
            run += v;
        }
    }
}

// ---------------- phase 3: per-chunk replay + output epilogue ----------------
__global__ __launch_bounds__(256) void scan_out(const float* __restrict__ z,
                                                const float* __restrict__ k_val,
                                                const float* __restrict__ p_w,
                                                const float* __restrict__ theta,
                                                const float* __restrict__ csum,
                                                const float* __restrict__ cden,
                                                const float* __restrict__ W_re,
                                                const float* __restrict__ W_im,
                                                const float* __restrict__ norm_scale,
                                                float* __restrict__ y) {
    const int idx = blockIdx.x;
    const int c = idx & (NCHUNK - 1);
    const int bk = idx / NCHUNK;
    const int k = bk & (K_TOT - 1);
    const int b = bk / K_TOT;
    const int t = threadIdx.x;
    const int h = t >> 3;
    const int m = t & 7;
    const int kq = k >> 3;   // K -> (K_Q, N_REP): kq = k / N_REP

    const float th = theta[(k * H_DIM + h) * M_DIM + m];
    size_t sbase = ((size_t)idx * 256 + t) * 2;
    float nre = csum[sbase];
    float nim = csum[sbase + 1];
    float den = cden[idx];

    const float wsc_re = norm_scale[h] * W_re[h * H_DIM + h];
    const float wsc_im = norm_scale[H_DIM + h] * W_im[h * H_DIM + h];

    const int l0 = c * CHUNK_L;
    for (int i = 0; i < CHUNK_L; i++) {
        const int l = l0 + i;
        const size_t bl = (size_t)b * L_SEQ + l;
        float p = p_w[bl * K_TOT + k];
        float kv = k_val[bl * DIM_K + k * H_DIM + h];
        float s, cs;
        sincosf(kv * th, &s, &cs);
        nre += p * cs;
        nim += p * s;
        den += p;
        float inv = 1.0f / fmaxf(den, 1e-4f);
        float sre = nre * inv;
        float sim = nim * inv;

        size_t qbase = bl * TOTAL_DIM + DIM_MEM +
                       (size_t)(((kq * H_DIM + h) * M_DIM + m) * 2);
        float qr = z[qbase];
        float qi = z[qbase + 1];

        float ore = sre * qr + sim * qi;
        float oim = sim * qr - sre * qi;

        // reduce over m: 8 consecutive lanes in same wave
        ore += __shfl_xor(ore, 1); oim += __shfl_xor(oim, 1);
        ore += __shfl_xor(ore, 2); oim += __shfl_xor(oim, 2);
        ore += __shfl_xor(ore, 4); oim += __shfl_xor(oim, 4);

        if (m == 0) {
            float v = ore * wsc_re + oim * wsc_im;
            float yv = v / (1.0f + expf(-v));   // silu
            y[bl * DIM_K + k * H_DIM + h] = yv;
        }
    }
}

// ---------------- launch ----------------
extern "C" void kernel_launch(void* const* d_in, const int* in_sizes, int n_in,
                              void* d_out, int out_size, void* d_ws, size_t ws_size,
                              hipStream_t stream) {
    const float* x            = (const float*)d_in[0];
    const float* W_in         = (const float*)d_in[1];
    const float* conv_k      = (const float*)d_in[2];
    const float* theta        = (const float*)d_in[3];
    const float* decay_slopes = (const float*)d_in[4];
    const float* anchor_slopes= (const float*)d_in[5];
    const float* score_scale  = (const float*)d_in[6];
    const float* W_re         = (const float*)d_in[7];
    const float* W_im         = (const float*)d_in[8];
    const float* norm_scale   = (const float*)d_in[9];
    const float* W_out        = (const float*)d_in[10];
    float* out = (float*)d_out;

    float* ws = (float*)d_ws;
    size_t off = 0;
    float* z     = ws + off; off += (size_t)BL_TOT * TOTAL_DIM;            // 12,713,984
    float* k_val = ws + off; off += (size_t)BL_TOT * DIM_K;                //  4,194,304
    float* p_w   = ws + off; off += (size_t)BL_TOT * K_TOT;                //    131,072
    float* y     = ws + off; off += (size_t)BL_TOT * DIM_K;                //  4,194,304
    float* csum  = ws + off; off += (size_t)B_SZ * K_TOT * NCHUNK * 256 * 2; // 1,048,576
    float* cden  = ws + off; off += (size_t)B_SZ * K_TOT * NCHUNK;         //      2,048

    // 1) z = x @ W_in   (4096 x 1024) @ (1024 x 3104)
    {
        dim3 grid((TOTAL_DIM + 63) / 64, BL_TOT / 64);
        gemm_f32<<<grid, 256, 0, stream>>>(x, W_in, z, BL_TOT, TOTAL_DIM, D_MODEL);
    }
    // 2) depthwise conv + p_w
    conv_pw<<<BL_TOT, 256, 0, stream>>>(z, conv_k, score_scale, decay_slopes,
                                        anchor_slopes, k_val, p_w);
    // 3) blocked scan
    chunk_sums<<<B_SZ * K_TOT * NCHUNK, 256, 0, stream>>>(k_val, p_w, theta, csum, cden);
    chunk_prefix<<<B_SZ * K_TOT, 256, 0, stream>>>(csum, cden);
    scan_out<<<B_SZ * K_TOT * NCHUNK, 256, 0, stream>>>(z, k_val, p_w, theta, csum,
                                                        cden, W_re, W_im, norm_scale, y);
    // 4) out = y @ W_out  (4096 x 1024) @ (1024 x 1024)
    {
        dim3 grid(D_MODEL / 64, BL_TOT / 64);
        gemm_f32<<<grid, 256, 0, stream>>>(y, W_out, out, BL_TOT, D_MODEL, D_MODEL);
    }
}

// Round 2
// 244.108 us; speedup vs baseline: 3.8278x; 3.8278x over previous
//
#include <hip/hip_runtime.h>
#include <hip/hip_bf16.h>
#include <math.h>

// ---------------- problem constants ----------------
#define D_MODEL   1024
#define K_TOT     32
#define N_DECAY   28
#define M_DIM     8
#define KS        4
#define H_DIM     32
#define DIM_K     1024
#define DIM_MEM   1056
#define TOTAL_DIM 3104
#define NPAD_IN   3200          // 25 * 128
#define B_SZ      2
#define L_SEQ     2048
#define BL_TOT    4096

#define NCHUNK    32
#define CHUNK_L   64

typedef __attribute__((ext_vector_type(8))) __bf16 bf16x8;
typedef __attribute__((ext_vector_type(4))) __bf16 bf16x4;
typedef __attribute__((ext_vector_type(4))) float  f32x4;

__device__ __forceinline__ void gload_lds16(const void* g, void* l) {
    __builtin_amdgcn_global_load_lds(
        (const __attribute__((address_space(1))) void*)g,
        (__attribute__((address_space(3))) void*)l, 16, 0, 0);
}

// ---------------- bf16 MFMA GEMM (m97 structure) ----------------
// C[M,N] f32 = A[M,K] bf16 (row-major) * Bt[N,K] bf16 (pre-transposed, rows padded)
// 128x128 tile, BK=32, 256 threads (4 waves, 2x2), 4x4 frags of 16x16x32.
template<bool CHECK_N>
__global__ __launch_bounds__(256) void gemm_bf16(const __bf16* __restrict__ A,
                                                 const __bf16* __restrict__ Bt,
                                                 float* __restrict__ C,
                                                 int Mdim, int Ndim, int Kdim) {
    __shared__ __bf16 As[128 * 32];
    __shared__ __bf16 Bs[128 * 32];

    const int tid  = threadIdx.x;
    const int w    = tid >> 6;
    const int lane = tid & 63;
    const int l15  = lane & 15;
    const int l16  = lane >> 4;            // k-octet 0..3
    const int wm   = w >> 1, wn = w & 1;

    const int r0   = blockIdx.y * 128;
    const int col0 = blockIdx.x * 128;

    f32x4 acc[4][4] = {};

    for (int k0 = 0; k0 < Kdim; k0 += 32) {
        // ---- stage A,B tiles: per wave 2+2 global_load_lds (16B/lane) ----
#pragma unroll
        for (int j = 0; j < 2; j++) {
            const int rblk = (j * 4 + w) * 16;          // 16 rows per load
            const int r    = rblk + (lane >> 2);
            const int ko   = (lane & 3) ^ (r & 3);      // pre-swizzled source octet
            gload_lds16(A + (size_t)(r0 + r) * Kdim + k0 + ko * 8,
                        &As[rblk * 32]);
        }
#pragma unroll
        for (int j = 0; j < 2; j++) {
            const int rblk = (j * 4 + w) * 16;
            const int r    = rblk + (lane >> 2);
            const int ko   = (lane & 3) ^ (r & 3);
            gload_lds16(Bt + (size_t)(col0 + r) * Kdim + k0 + ko * 8,
                        &Bs[rblk * 32]);
        }
        __syncthreads();   // drains vmcnt(0): tiles ready

        // ---- fragments (swizzled ds_read_b128) + MFMA ----
        bf16x8 a[4], b[4];
#pragma unroll
        for (int mi = 0; mi < 4; mi++) {
            const int row = wm * 64 + mi * 16 + l15;
            a[mi] = *(const bf16x8*)&As[row * 32 + ((l16 ^ (row & 3)) << 3)];
        }
#pragma unroll
        for (int ni = 0; ni < 4; ni++) {
            const int col = wn * 64 + ni * 16 + l15;
            b[ni] = *(const bf16x8*)&Bs[col * 32 + ((l16 ^ (col & 3)) << 3)];
        }
#pragma unroll
        for (int mi = 0; mi < 4; mi++)
#pragma unroll
            for (int ni = 0; ni < 4; ni++)
                acc[mi][ni] = __builtin_amdgcn_mfma_f32_16x16x32_bf16(
                    a[mi], b[ni], acc[mi][ni], 0, 0, 0);
        __syncthreads();   // all ds_reads done before next stage overwrites
    }

    // ---- epilogue: C/D layout col=lane&15, row=(lane>>4)*4+q ----
#pragma unroll
    for (int mi = 0; mi < 4; mi++) {
#pragma unroll
        for (int ni = 0; ni < 4; ni++) {
            const int col = col0 + wn * 64 + ni * 16 + l15;
            if (CHECK_N && col >= Ndim) continue;
            const int row = r0 + wm * 64 + mi * 16 + l16 * 4;
#pragma unroll
            for (int q = 0; q < 4; q++)
                C[(size_t)(row + q) * Ndim + col] = acc[mi][ni][q];
        }
    }
}

// ---------------- straight cast fp32 -> bf16 (vectorized) ----------------
__global__ __launch_bounds__(256) void cast_bf16(const float* __restrict__ in,
                                                 __bf16* __restrict__ out, int n4) {
    const int i = blockIdx.x * blockDim.x + threadIdx.x;
    if (i >= n4) return;
    const float4 v = ((const float4*)in)[i];
    bf16x4 o;
    o.x = (__bf16)v.x; o.y = (__bf16)v.y; o.z = (__bf16)v.z; o.w = (__bf16)v.w;
    ((bf16x4*)out)[i] = o;
}

// ---------------- transpose-cast: W[K,N] f32 -> Wt[Npad,K] bf16 (zero pad) ---
__global__ __launch_bounds__(256) void transpose_cast(const float* __restrict__ W,
                                                      __bf16* __restrict__ Wt,
                                                      int Kdim, int Ndim, int Npad) {
    __shared__ float tile[32][33];
    const int n0 = blockIdx.x * 32, k0 = blockIdx.y * 32;
    const int tx = threadIdx.x & 31, ty = threadIdx.x >> 5;   // 32 x 8
#pragma unroll
    for (int i = 0; i < 32; i += 8) {
        float v = 0.f;
        if (n0 + tx < Ndim) v = W[(size_t)(k0 + ty + i) * Ndim + n0 + tx];
        tile[ty + i][tx] = v;
    }
    __syncthreads();
#pragma unroll
    for (int i = 0; i < 32; i += 8) {
        const int n = n0 + ty + i;
        if (n < Npad) Wt[(size_t)n * Kdim + k0 + tx] = (__bf16)tile[tx][ty + i];
    }
}

// ---------------- depthwise causal conv + gate weights ----------------
__global__ __launch_bounds__(256) void conv_pw(const float* __restrict__ z,
                                               const float* __restrict__ conv_k,
                                               const float* __restrict__ score_scale,
                                               const float* __restrict__ decay_slopes,
                                               const float* __restrict__ anchor_slopes,
                                               float* __restrict__ k_val,
                                               float* __restrict__ p_w) {
    const int bl = blockIdx.x;
    const int l = bl & (L_SEQ - 1);
    const int b = bl >> 11;

    for (int c = threadIdx.x; c < DIM_MEM; c += blockDim.x) {
        float acc = 0.f;
#pragma unroll
        for (int s = 0; s < KS; s++) {
            int t = l - (KS - 1) + s;
            if (t >= 0)
                acc += conv_k[s * DIM_MEM + c] *
                       z[((size_t)b * L_SEQ + t) * TOTAL_DIM + c];
        }
        if (c < DIM_K) {
            k_val[(size_t)bl * DIM_K + c] = acc;
        } else {
            int k = c - DIM_K;
            float lp = fminf(fmaxf(score_scale[k] * acc, -20.f), 20.f);
            float lt;
            if (k < N_DECAY) {
                float sd = log1pf(expf(decay_slopes[k]));
                lt = -sd * (float)(L_SEQ - 1 - l);
            } else {
                float sa = log1pf(expf(anchor_slopes[k - N_DECAY]));
                lt = -sa * (float)l;
            }
            p_w[(size_t)bl * K_TOT + k] = expf(lp + lt);
        }
    }
}

// ---------------- phase 1: per-chunk totals ----------------
__global__ __launch_bounds__(256) void chunk_sums(const float* __restrict__ k_val,
                                                  const float* __restrict__ p_w,
                                                  const float* __restrict__ theta,
                                                  float* __restrict__ csum,
                                                  float* __restrict__ cden) {
    const int idx = blockIdx.x;
    const int c = idx & (NCHUNK - 1);
    const int bk = idx / NCHUNK;
    const int k = bk & (K_TOT - 1);
    const int b = bk / K_TOT;
    const int t = threadIdx.x;
    const int h = t >> 3;
    const int m = t & 7;

    const float th = theta[(k * H_DIM + h) * M_DIM + m];
    float sre = 0.f, sim = 0.f, sden = 0.f;
    const int l0 = c * CHUNK_L;
    for (int i = 0; i < CHUNK_L; i++) {
        size_t bl = (size_t)b * L_SEQ + (l0 + i);
        float p = p_w[bl * K_TOT + k];
        float kv = k_val[bl * DIM_K + k * H_DIM + h];
        float s, cs;
        sincosf(kv * th, &s, &cs);
        sre += p * cs;
        sim += p * s;
        sden += p;
    }
    size_t base = ((size_t)idx * 256 + t) * 2;
    csum[base] = sre;
    csum[base + 1] = sim;
    if (t == 0) cden[idx] = sden;
}

// ---------------- phase 2: exclusive prefix over chunks ----------------
__global__ __launch_bounds__(256) void chunk_prefix(float* __restrict__ csum,
                                                    float* __restrict__ cden) {
    const int bk = blockIdx.x;
    const int t = threadIdx.x;
    float run_re = 0.f, run_im = 0.f;
    for (int c = 0; c < NCHUNK; c++) {
        size_t base = (((size_t)bk * NCHUNK + c) * 256 + t) * 2;
        float re = csum[base], im = csum[base + 1];
        csum[base] = run_re;
        csum[base + 1] = run_im;
        run_re += re;
        run_im += im;
    }
    if (t == 0) {
        float run = 0.f;
        for (int c = 0; c < NCHUNK; c++) {
            float v = cden[bk * NCHUNK + c];
            cden[bk * NCHUNK + c] = run;
            run += v;
        }
    }
}

// ---------------- phase 3: per-chunk replay + output epilogue ----------------
__global__ __launch_bounds__(256) void scan_out(const float* __restrict__ z,
                                                const float* __restrict__ k_val,
                                                const float* __restrict__ p_w,
                                                const float* __restrict__ theta,
                                                const float* __restrict__ csum,
                                                const float* __restrict__ cden,
                                                const float* __restrict__ W_re,
                                                const float* __restrict__ W_im,
                                                const float* __restrict__ norm_scale,
                                                __bf16* __restrict__ y) {
    const int idx = blockIdx.x;
    const int c = idx & (NCHUNK - 1);
    const int bk = idx / NCHUNK;
    const int k = bk & (K_TOT - 1);
    const int b = bk / K_TOT;
    const int t = threadIdx.x;
    const int h = t >> 3;
    const int m = t & 7;
    const int kq = k >> 3;

    const float th = theta[(k * H_DIM + h) * M_DIM + m];
    size_t sbase = ((size_t)idx * 256 + t) * 2;
    float nre = csum[sbase];
    float nim = csum[sbase + 1];
    float den = cden[idx];

    const float wsc_re = norm_scale[h] * W_re[h * H_DIM + h];
    const float wsc_im = norm_scale[H_DIM + h] * W_im[h * H_DIM + h];

    const int l0 = c * CHUNK_L;
    for (int i = 0; i < CHUNK_L; i++) {
        const int l = l0 + i;
        const size_t bl = (size_t)b * L_SEQ + l;
        float p = p_w[bl * K_TOT + k];
        float kv = k_val[bl * DIM_K + k * H_DIM + h];
        float s, cs;
        sincosf(kv * th, &s, &cs);
        nre += p * cs;
        nim += p * s;
        den += p;
        float inv = 1.0f / fmaxf(den, 1e-4f);
        float sre = nre * inv;
        float sim = nim * inv;

        size_t qbase = bl * TOTAL_DIM + DIM_MEM +
                       (size_t)(((kq * H_DIM + h) * M_DIM + m) * 2);
        float qr = z[qbase];
        float qi = z[qbase + 1];

        float ore = sre * qr + sim * qi;
        float oim = sim * qr - sre * qi;

        ore += __shfl_xor(ore, 1); oim += __shfl_xor(oim, 1);
        ore += __shfl_xor(ore, 2); oim += __shfl_xor(oim, 2);
        ore += __shfl_xor(ore, 4); oim += __shfl_xor(oim, 4);

        if (m == 0) {
            float v = ore * wsc_re + oim * wsc_im;
            float yv = v / (1.0f + expf(-v));
            y[bl * DIM_K + k * H_DIM + h] = (__bf16)yv;
        }
    }
}

// ---------------- launch ----------------
extern "C" void kernel_launch(void* const* d_in, const int* in_sizes, int n_in,
                              void* d_out, int out_size, void* d_ws, size_t ws_size,
                              hipStream_t stream) {
    const float* x            = (const float*)d_in[0];
    const float* W_in         = (const float*)d_in[1];
    const float* conv_k       = (const float*)d_in[2];
    const float* theta        = (const float*)d_in[3];
    const float* decay_slopes = (const float*)d_in[4];
    const float* anchor_slopes= (const float*)d_in[5];
    const float* score_scale  = (const float*)d_in[6];
    const float* W_re         = (const float*)d_in[7];
    const float* W_im         = (const float*)d_in[8];
    const float* norm_scale   = (const float*)d_in[9];
    const float* W_out        = (const float*)d_in[10];
    float* out = (float*)d_out;

    float* ws = (float*)d_ws;
    size_t off = 0;
    float* z      = ws + off; off += (size_t)BL_TOT * TOTAL_DIM;              // 12,713,984
    float* k_val  = ws + off; off += (size_t)BL_TOT * DIM_K;                  //  4,194,304
    float* p_w    = ws + off; off += (size_t)BL_TOT * K_TOT;                  //    131,072
    float* csum   = ws + off; off += (size_t)B_SZ * K_TOT * NCHUNK * 256 * 2; //  1,048,576
    float* cden   = ws + off; off += (size_t)B_SZ * K_TOT * NCHUNK;           //      2,048
    __bf16* x_b     = (__bf16*)(ws + off); off += (size_t)BL_TOT * D_MODEL / 2;
    __bf16* W_in_T  = (__bf16*)(ws + off); off += (size_t)NPAD_IN * D_MODEL / 2;
    __bf16* W_out_T = (__bf16*)(ws + off); off += (size_t)D_MODEL * D_MODEL / 2;
    __bf16* y_b     = (__bf16*)(ws + off); off += (size_t)BL_TOT * DIM_K / 2;

    // prep: casts / transposes
    cast_bf16<<<(BL_TOT * D_MODEL / 4 + 255) / 256, 256, 0, stream>>>(
        x, x_b, BL_TOT * D_MODEL / 4);
    {
        dim3 g(NPAD_IN / 32, D_MODEL / 32);
        transpose_cast<<<g, 256, 0, stream>>>(W_in, W_in_T, D_MODEL, TOTAL_DIM, NPAD_IN);
    }
    {
        dim3 g(D_MODEL / 32, D_MODEL / 32);
        transpose_cast<<<g, 256, 0, stream>>>(W_out, W_out_T, D_MODEL, D_MODEL, D_MODEL);
    }

    // 1) z = x @ W_in (MFMA bf16)
    {
        dim3 grid(NPAD_IN / 128, BL_TOT / 128);
        gemm_bf16<true><<<grid, 256, 0, stream>>>(x_b, W_in_T, z,
                                                  BL_TOT, TOTAL_DIM, D_MODEL);
    }
    // 2) depthwise conv + p_w
    conv_pw<<<BL_TOT, 256, 0, stream>>>(z, conv_k, score_scale, decay_slopes,
                                        anchor_slopes, k_val, p_w);
    // 3) blocked scan
    chunk_sums<<<B_SZ * K_TOT * NCHUNK, 256, 0, stream>>>(k_val, p_w, theta, csum, cden);
    chunk_prefix<<<B_SZ * K_TOT, 256, 0, stream>>>(csum, cden);
    scan_out<<<B_SZ * K_TOT * NCHUNK, 256, 0, stream>>>(z, k_val, p_w, theta, csum,
                                                        cden, W_re, W_im, norm_scale, y_b);
    // 4) out = y @ W_out (MFMA bf16)
    {
        dim3 grid(D_MODEL / 128, BL_TOT / 128);
        gemm_bf16<false><<<grid, 256, 0, stream>>>(y_b, W_out_T, out,
                                                   BL_TOT, D_MODEL, D_MODEL);
    }
}

// Round 3
// 168.450 us; speedup vs baseline: 5.5470x; 1.4491x over previous
//
#include <hip/hip_runtime.h>
#include <hip/hip_bf16.h>
#include <math.h>

// ---------------- problem constants ----------------
#define D_MODEL   1024
#define K_TOT     32
#define N_DECAY   28
#define M_DIM     8
#define KS        4
#define H_DIM     32
#define DIM_K     1024
#define DIM_MEM   1056
#define TOTAL_DIM 3104
#define NPAD_IN   3200          // 25 * 128
#define B_SZ      2
#define L_SEQ     2048
#define BL_TOT    4096

#define KG_CNT    4             // k-groups of 8 (one kq each)
#define NCHUNK    64
#define CHUNK_L   32            // L_SEQ / NCHUNK

typedef __attribute__((ext_vector_type(8))) __bf16 bf16x8;
typedef __attribute__((ext_vector_type(4))) __bf16 bf16x4;
typedef __attribute__((ext_vector_type(4))) float  f32x4;

__device__ __forceinline__ void gload_lds16(const void* g, void* l) {
    __builtin_amdgcn_global_load_lds(
        (const __attribute__((address_space(1))) void*)g,
        (__attribute__((address_space(3))) void*)l, 16, 0, 0);
}

// ---------------- bf16 MFMA GEMM (m97 structure) ----------------
template<bool CHECK_N>
__global__ __launch_bounds__(256) void gemm_bf16(const __bf16* __restrict__ A,
                                                 const __bf16* __restrict__ Bt,
                                                 float* __restrict__ C,
                                                 int Mdim, int Ndim, int Kdim) {
    __shared__ __bf16 As[128 * 32];
    __shared__ __bf16 Bs[128 * 32];

    const int tid  = threadIdx.x;
    const int w    = tid >> 6;
    const int lane = tid & 63;
    const int l15  = lane & 15;
    const int l16  = lane >> 4;
    const int wm   = w >> 1, wn = w & 1;

    const int r0   = blockIdx.y * 128;
    const int col0 = blockIdx.x * 128;

    f32x4 acc[4][4] = {};

    for (int k0 = 0; k0 < Kdim; k0 += 32) {
#pragma unroll
        for (int j = 0; j < 2; j++) {
            const int rblk = (j * 4 + w) * 16;
            const int r    = rblk + (lane >> 2);
            const int ko   = (lane & 3) ^ (r & 3);
            gload_lds16(A + (size_t)(r0 + r) * Kdim + k0 + ko * 8,
                        &As[rblk * 32]);
        }
#pragma unroll
        for (int j = 0; j < 2; j++) {
            const int rblk = (j * 4 + w) * 16;
            const int r    = rblk + (lane >> 2);
            const int ko   = (lane & 3) ^ (r & 3);
            gload_lds16(Bt + (size_t)(col0 + r) * Kdim + k0 + ko * 8,
                        &Bs[rblk * 32]);
        }
        __syncthreads();

        bf16x8 a[4], b[4];
#pragma unroll
        for (int mi = 0; mi < 4; mi++) {
            const int row = wm * 64 + mi * 16 + l15;
            a[mi] = *(const bf16x8*)&As[row * 32 + ((l16 ^ (row & 3)) << 3)];
        }
#pragma unroll
        for (int ni = 0; ni < 4; ni++) {
            const int col = wn * 64 + ni * 16 + l15;
            b[ni] = *(const bf16x8*)&Bs[col * 32 + ((l16 ^ (col & 3)) << 3)];
        }
#pragma unroll
        for (int mi = 0; mi < 4; mi++)
#pragma unroll
            for (int ni = 0; ni < 4; ni++)
                acc[mi][ni] = __builtin_amdgcn_mfma_f32_16x16x32_bf16(
                    a[mi], b[ni], acc[mi][ni], 0, 0, 0);
        __syncthreads();
    }

#pragma unroll
    for (int mi = 0; mi < 4; mi++) {
#pragma unroll
        for (int ni = 0; ni < 4; ni++) {
            const int col = col0 + wn * 64 + ni * 16 + l15;
            if (CHECK_N && col >= Ndim) continue;
            const int row = r0 + wm * 64 + mi * 16 + l16 * 4;
#pragma unroll
            for (int q = 0; q < 4; q++)
                C[(size_t)(row + q) * Ndim + col] = acc[mi][ni][q];
        }
    }
}

// ---------------- straight cast fp32 -> bf16 ----------------
__global__ __launch_bounds__(256) void cast_bf16(const float* __restrict__ in,
                                                 __bf16* __restrict__ out, int n4) {
    const int i = blockIdx.x * blockDim.x + threadIdx.x;
    if (i >= n4) return;
    const float4 v = ((const float4*)in)[i];
    bf16x4 o;
    o.x = (__bf16)v.x; o.y = (__bf16)v.y; o.z = (__bf16)v.z; o.w = (__bf16)v.w;
    ((bf16x4*)out)[i] = o;
}

// ---------------- transpose-cast: W[K,N] f32 -> Wt[Npad,K] bf16 ----------------
__global__ __launch_bounds__(256) void transpose_cast(const float* __restrict__ W,
                                                      __bf16* __restrict__ Wt,
                                                      int Kdim, int Ndim, int Npad) {
    __shared__ float tile[32][33];
    const int n0 = blockIdx.x * 32, k0 = blockIdx.y * 32;
    const int tx = threadIdx.x & 31, ty = threadIdx.x >> 5;
#pragma unroll
    for (int i = 0; i < 32; i += 8) {
        float v = 0.f;
        if (n0 + tx < Ndim) v = W[(size_t)(k0 + ty + i) * Ndim + n0 + tx];
        tile[ty + i][tx] = v;
    }
    __syncthreads();
#pragma unroll
    for (int i = 0; i < 32; i += 8) {
        const int n = n0 + ty + i;
        if (n < Npad) Wt[(size_t)n * Kdim + k0 + tx] = (__bf16)tile[tx][ty + i];
    }
}

// ---------------- depthwise causal conv + gate weights ----------------
__global__ __launch_bounds__(256) void conv_pw(const float* __restrict__ z,
                                               const float* __restrict__ conv_k,
                                               const float* __restrict__ score_scale,
                                               const float* __restrict__ decay_slopes,
                                               const float* __restrict__ anchor_slopes,
                                               float* __restrict__ k_val,
                                               float* __restrict__ p_w) {
    const int bl = blockIdx.x;
    const int l = bl & (L_SEQ - 1);
    const int b = bl >> 11;

    for (int c = threadIdx.x; c < DIM_MEM; c += blockDim.x) {
        float acc = 0.f;
#pragma unroll
        for (int s = 0; s < KS; s++) {
            int t = l - (KS - 1) + s;
            if (t >= 0)
                acc += conv_k[s * DIM_MEM + c] *
                       z[((size_t)b * L_SEQ + t) * TOTAL_DIM + c];
        }
        if (c < DIM_K) {
            k_val[(size_t)bl * DIM_K + c] = acc;
        } else {
            int k = c - DIM_K;
            float lp = fminf(fmaxf(score_scale[k] * acc, -20.f), 20.f);
            float lt;
            if (k < N_DECAY) {
                float sd = log1pf(__expf(decay_slopes[k]));
                lt = -sd * (float)(L_SEQ - 1 - l);
            } else {
                float sa = log1pf(__expf(anchor_slopes[k - N_DECAY]));
                lt = -sa * (float)l;
            }
            p_w[(size_t)bl * K_TOT + k] = __expf(lp + lt);
        }
    }
}

// ---------------- phase 1: per-chunk totals (m in-register) ----------------
// blockIdx.x = (b*KG + kg)*NCHUNK + c ; thread t: kl = t>>5, h = t&31
__global__ __launch_bounds__(256) void chunk_sums(const float* __restrict__ k_val,
                                                  const float* __restrict__ p_w,
                                                  const float* __restrict__ theta,
                                                  float* __restrict__ csum,
                                                  float* __restrict__ cden) {
    const int idx = blockIdx.x;
    const int c = idx & (NCHUNK - 1);
    const int bkg = idx / NCHUNK;
    const int kg = bkg & (KG_CNT - 1);
    const int b = bkg / KG_CNT;
    const int t = threadIdx.x;
    const int kl = t >> 5;
    const int h = t & 31;
    const int k = kg * 8 + kl;
    const int bk = b * K_TOT + k;

    float th[M_DIM];
    {
        const float4 t0 = *(const float4*)&theta[(k * H_DIM + h) * M_DIM];
        const float4 t1 = *(const float4*)&theta[(k * H_DIM + h) * M_DIM + 4];
        th[0] = t0.x; th[1] = t0.y; th[2] = t0.z; th[3] = t0.w;
        th[4] = t1.x; th[5] = t1.y; th[6] = t1.z; th[7] = t1.w;
    }

    float nre[M_DIM] = {}, nim[M_DIM] = {};
    float den = 0.f;
    const int l0 = c * CHUNK_L;
#pragma unroll 4
    for (int i = 0; i < CHUNK_L; i++) {
        const size_t bl = (size_t)b * L_SEQ + (l0 + i);
        const float p  = p_w[bl * K_TOT + k];
        const float kv = k_val[bl * DIM_K + k * H_DIM + h];
#pragma unroll
        for (int m = 0; m < M_DIM; m++) {
            const float phi = kv * th[m];
            nre[m] = fmaf(p, __cosf(phi), nre[m]);
            nim[m] = fmaf(p, __sinf(phi), nim[m]);
        }
        den += p;
    }

    float* base = &csum[(((size_t)bk * NCHUNK + c) * 256 + h * M_DIM) * 2];
#pragma unroll
    for (int j = 0; j < 4; j++) {
        f32x4 v = { nre[2 * j], nim[2 * j], nre[2 * j + 1], nim[2 * j + 1] };
        ((f32x4*)base)[j] = v;
    }
    if (h == 0) cden[bk * NCHUNK + c] = den;
}

// ---------------- phase 2: exclusive prefix over chunks ----------------
__global__ __launch_bounds__(256) void chunk_prefix(float* __restrict__ csum,
                                                    float* __restrict__ cden) {
    const int bk = blockIdx.x;
    const int t = threadIdx.x;

    // den: wave-parallel exclusive scan over the 64 chunks (wave 0)
    if (t < 64) {
        const float orig = cden[bk * NCHUNK + t];
        float v = orig;
#pragma unroll
        for (int d = 1; d < 64; d <<= 1) {
            const float u = __shfl_up(v, d);
            if (t >= d) v += u;
        }
        cden[bk * NCHUNK + t] = v - orig;
    }

    float run_re = 0.f, run_im = 0.f;
    for (int c = 0; c < NCHUNK; c++) {
        float2* p = (float2*)&csum[(((size_t)bk * NCHUNK + c) * 256 + t) * 2];
        const float2 v = *p;
        *p = make_float2(run_re, run_im);
        run_re += v.x;
        run_im += v.y;
    }
}

// ---------------- phase 3: per-chunk replay + output epilogue ----------------
__global__ __launch_bounds__(256) void scan_out(const float* __restrict__ z,
                                                const float* __restrict__ k_val,
                                                const float* __restrict__ p_w,
                                                const float* __restrict__ theta,
                                                const float* __restrict__ csum,
                                                const float* __restrict__ cden,
                                                const float* __restrict__ W_re,
                                                const float* __restrict__ W_im,
                                                const float* __restrict__ norm_scale,
                                                __bf16* __restrict__ y) {
    const int idx = blockIdx.x;
    const int c = idx & (NCHUNK - 1);
    const int bkg = idx / NCHUNK;
    const int kg = bkg & (KG_CNT - 1);
    const int b = bkg / KG_CNT;
    const int t = threadIdx.x;
    const int kl = t >> 5;
    const int h = t & 31;
    const int k = kg * 8 + kl;
    const int bk = b * K_TOT + k;

    float th[M_DIM];
    {
        const float4 t0 = *(const float4*)&theta[(k * H_DIM + h) * M_DIM];
        const float4 t1 = *(const float4*)&theta[(k * H_DIM + h) * M_DIM + 4];
        th[0] = t0.x; th[1] = t0.y; th[2] = t0.z; th[3] = t0.w;
        th[4] = t1.x; th[5] = t1.y; th[6] = t1.z; th[7] = t1.w;
    }

    float nre[M_DIM], nim[M_DIM];
    {
        const float* base = &csum[(((size_t)bk * NCHUNK + c) * 256 + h * M_DIM) * 2];
#pragma unroll
        for (int j = 0; j < 4; j++) {
            const f32x4 v = ((const f32x4*)base)[j];
            nre[2 * j] = v.x; nim[2 * j] = v.y;
            nre[2 * j + 1] = v.z; nim[2 * j + 1] = v.w;
        }
    }
    float den = cden[bk * NCHUNK + c];

    const float wsc_re = norm_scale[h] * W_re[h * H_DIM + h];
    const float wsc_im = norm_scale[H_DIM + h] * W_im[h * H_DIM + h];

    const int l0 = c * CHUNK_L;
    for (int i = 0; i < CHUNK_L; i++) {
        const size_t bl = (size_t)b * L_SEQ + (l0 + i);
        const float p  = p_w[bl * K_TOT + k];
        const float kv = k_val[bl * DIM_K + k * H_DIM + h];

        // q: 16 consecutive floats (m, re/im)
        const float* qp = &z[bl * TOTAL_DIM + DIM_MEM + (size_t)(kg * H_DIM + h) * 16];
        float qr[M_DIM], qi[M_DIM];
#pragma unroll
        for (int j = 0; j < 4; j++) {
            const float4 v = ((const float4*)qp)[j];
            qr[2 * j] = v.x; qi[2 * j] = v.y;
            qr[2 * j + 1] = v.z; qi[2 * j + 1] = v.w;
        }

        float ore = 0.f, oim = 0.f;
#pragma unroll
        for (int m = 0; m < M_DIM; m++) {
            const float phi = kv * th[m];
            nre[m] = fmaf(p, __cosf(phi), nre[m]);
            nim[m] = fmaf(p, __sinf(phi), nim[m]);
            ore = fmaf(nre[m], qr[m], fmaf(nim[m], qi[m], ore));
            oim = fmaf(nim[m], qr[m], fmaf(-nre[m], qi[m], oim));
        }
        den += p;
        const float inv = __builtin_amdgcn_rcpf(fmaxf(den, 1e-4f));

        const float v = (ore * wsc_re + oim * wsc_im) * inv;
        const float yv = v * __builtin_amdgcn_rcpf(1.0f + __expf(-v));
        y[bl * DIM_K + k * H_DIM + h] = (__bf16)yv;
    }
}

// ---------------- launch ----------------
extern "C" void kernel_launch(void* const* d_in, const int* in_sizes, int n_in,
                              void* d_out, int out_size, void* d_ws, size_t ws_size,
                              hipStream_t stream) {
    const float* x            = (const float*)d_in[0];
    const float* W_in         = (const float*)d_in[1];
    const float* conv_k       = (const float*)d_in[2];
    const float* theta        = (const float*)d_in[3];
    const float* decay_slopes = (const float*)d_in[4];
    const float* anchor_slopes= (const float*)d_in[5];
    const float* score_scale  = (const float*)d_in[6];
    const float* W_re         = (const float*)d_in[7];
    const float* W_im         = (const float*)d_in[8];
    const float* norm_scale   = (const float*)d_in[9];
    const float* W_out        = (const float*)d_in[10];
    float* out = (float*)d_out;

    float* ws = (float*)d_ws;
    size_t off = 0;
    float* z      = ws + off; off += (size_t)BL_TOT * TOTAL_DIM;
    float* k_val  = ws + off; off += (size_t)BL_TOT * DIM_K;
    float* p_w    = ws + off; off += (size_t)BL_TOT * K_TOT;
    float* csum   = ws + off; off += (size_t)B_SZ * K_TOT * NCHUNK * 256 * 2;
    float* cden   = ws + off; off += (size_t)B_SZ * K_TOT * NCHUNK;
    __bf16* x_b     = (__bf16*)(ws + off); off += (size_t)BL_TOT * D_MODEL / 2;
    __bf16* W_in_T  = (__bf16*)(ws + off); off += (size_t)NPAD_IN * D_MODEL / 2;
    __bf16* W_out_T = (__bf16*)(ws + off); off += (size_t)D_MODEL * D_MODEL / 2;
    __bf16* y_b     = (__bf16*)(ws + off); off += (size_t)BL_TOT * DIM_K / 2;

    cast_bf16<<<(BL_TOT * D_MODEL / 4 + 255) / 256, 256, 0, stream>>>(
        x, x_b, BL_TOT * D_MODEL / 4);
    {
        dim3 g(NPAD_IN / 32, D_MODEL / 32);
        transpose_cast<<<g, 256, 0, stream>>>(W_in, W_in_T, D_MODEL, TOTAL_DIM, NPAD_IN);
    }
    {
        dim3 g(D_MODEL / 32, D_MODEL / 32);
        transpose_cast<<<g, 256, 0, stream>>>(W_out, W_out_T, D_MODEL, D_MODEL, D_MODEL);
    }

    // 1) z = x @ W_in (MFMA bf16)
    {
        dim3 grid(NPAD_IN / 128, BL_TOT / 128);
        gemm_bf16<true><<<grid, 256, 0, stream>>>(x_b, W_in_T, z,
                                                  BL_TOT, TOTAL_DIM, D_MODEL);
    }
    // 2) depthwise conv + p_w
    conv_pw<<<BL_TOT, 256, 0, stream>>>(z, conv_k, score_scale, decay_slopes,
                                        anchor_slopes, k_val, p_w);
    // 3) blocked scan
    chunk_sums<<<B_SZ * KG_CNT * NCHUNK, 256, 0, stream>>>(k_val, p_w, theta, csum, cden);
    chunk_prefix<<<B_SZ * K_TOT, 256, 0, stream>>>(csum, cden);
    scan_out<<<B_SZ * KG_CNT * NCHUNK, 256, 0, stream>>>(z, k_val, p_w, theta, csum,
                                                         cden, W_re, W_im, norm_scale, y_b);
    // 4) out = y @ W_out (MFMA bf16)
    {
        dim3 grid(D_MODEL / 128, BL_TOT / 128);
        gemm_bf16<false><<<grid, 256, 0, stream>>>(y_b, W_out_T, out,
                                                   BL_TOT, D_MODEL, D_MODEL);
    }
}

// Round 4
// 144.365 us; speedup vs baseline: 6.4724x; 1.1668x over previous
//
#include <hip/hip_runtime.h>
#include <hip/hip_bf16.h>
#include <math.h>

// ---------------- problem constants ----------------
#define D_MODEL   1024
#define K_TOT     32
#define N_DECAY   28
#define M_DIM     8
#define KS        4
#define H_DIM     32
#define DIM_K     1024
#define DIM_MEM   1056
#define DIM_Q     2048
#define TOTAL_DIM 3104
#define NPAD_IN   3200          // 25 * 128
#define B_SZ      2
#define L_SEQ     2048
#define BL_TOT    4096

#define KG_CNT    4             // k-groups of 8
#define NCHUNK    64
#define CHUNK_L   32            // L_SEQ / NCHUNK

typedef __attribute__((ext_vector_type(8))) __bf16 bf16x8;
typedef __attribute__((ext_vector_type(4))) __bf16 bf16x4;
typedef __attribute__((ext_vector_type(4))) float  f32x4;

__device__ __forceinline__ void gload_lds16(const void* g, void* l) {
    __builtin_amdgcn_global_load_lds(
        (const __attribute__((address_space(1))) void*)g,
        (__attribute__((address_space(3))) void*)l, 16, 0, 0);
}

// ---------------- bf16 MFMA GEMM, BK=64, swizzled LDS, XCD-chunked grid ------
// EPI=0: C[M,N] f32 plain. EPI=1: split -> cols<1056 f32 z_mem (stride 1056),
//         cols in [1056,3104) bf16 q_b (stride 2048), cols>=3104 dropped.
template<int EPI>
__global__ __launch_bounds__(256) void gemm_bf16(const __bf16* __restrict__ A,
                                                 const __bf16* __restrict__ Bt,
                                                 float* __restrict__ C,
                                                 __bf16* __restrict__ Cq,
                                                 int Ndim, int Kdim, int gx) {
    __shared__ __bf16 As[128 * 64];
    __shared__ __bf16 Bs[128 * 64];

    // XCD-chunked bijective swizzle (nwg % 8 == 0 for all our grids)
    const int nwg = gridDim.x;
    int lin = blockIdx.x;
    lin = (lin & 7) * (nwg >> 3) + (lin >> 3);
    const int bx = lin % gx, by = lin / gx;
    const int r0 = by * 128, col0 = bx * 128;

    const int tid  = threadIdx.x;
    const int w    = tid >> 6;
    const int lane = tid & 63;
    const int l15  = lane & 15;
    const int l16  = lane >> 4;
    const int wm   = w >> 1, wn = w & 1;

    const int srow = w * 8 + (lane >> 3);   // row within 32-row stage group
    const int sslot = lane & 7;             // 16B slot within 128B row

    f32x4 acc[4][4] = {};

    for (int k0 = 0; k0 < Kdim; k0 += 64) {
#pragma unroll
        for (int j = 0; j < 4; j++) {
            const int r  = j * 32 + srow;
            const int so = sslot ^ (r & 7);          // inverse-swizzled source
            gload_lds16(A + (size_t)(r0 + r) * Kdim + k0 + so * 8,
                        &As[(j * 32 + w * 8) * 64]);
        }
#pragma unroll
        for (int j = 0; j < 4; j++) {
            const int r  = j * 32 + srow;
            const int so = sslot ^ (r & 7);
            gload_lds16(Bt + (size_t)(col0 + r) * Kdim + k0 + so * 8,
                        &Bs[(j * 32 + w * 8) * 64]);
        }
        __syncthreads();

#pragma unroll
        for (int kk = 0; kk < 2; kk++) {
            bf16x8 a[4], b[4];
#pragma unroll
            for (int mi = 0; mi < 4; mi++) {
                const int row  = wm * 64 + mi * 16 + l15;
                const int slot = (kk * 4 + l16) ^ (row & 7);
                a[mi] = *(const bf16x8*)&As[row * 64 + slot * 8];
            }
#pragma unroll
            for (int ni = 0; ni < 4; ni++) {
                const int col  = wn * 64 + ni * 16 + l15;
                const int slot = (kk * 4 + l16) ^ (col & 7);
                b[ni] = *(const bf16x8*)&Bs[col * 64 + slot * 8];
            }
#pragma unroll
            for (int mi = 0; mi < 4; mi++)
#pragma unroll
                for (int ni = 0; ni < 4; ni++)
                    acc[mi][ni] = __builtin_amdgcn_mfma_f32_16x16x32_bf16(
                        a[mi], b[ni], acc[mi][ni], 0, 0, 0);
        }
        __syncthreads();
    }

#pragma unroll
    for (int mi = 0; mi < 4; mi++) {
#pragma unroll
        for (int ni = 0; ni < 4; ni++) {
            const int col = col0 + wn * 64 + ni * 16 + l15;
            const int row = r0 + wm * 64 + mi * 16 + l16 * 4;
            if (EPI == 0) {
#pragma unroll
                for (int q = 0; q < 4; q++)
                    C[(size_t)(row + q) * Ndim + col] = acc[mi][ni][q];
            } else {
                if (col < DIM_MEM) {
#pragma unroll
                    for (int q = 0; q < 4; q++)
                        C[(size_t)(row + q) * DIM_MEM + col] = acc[mi][ni][q];
                } else if (col < TOTAL_DIM) {
#pragma unroll
                    for (int q = 0; q < 4; q++)
                        Cq[(size_t)(row + q) * DIM_Q + (col - DIM_MEM)] =
                            (__bf16)acc[mi][ni][q];
                }
            }
        }
    }
}

// ---------------- straight cast fp32 -> bf16 ----------------
__global__ __launch_bounds__(256) void cast_bf16(const float* __restrict__ in,
                                                 __bf16* __restrict__ out, int n4) {
    const int i = blockIdx.x * blockDim.x + threadIdx.x;
    if (i >= n4) return;
    const float4 v = ((const float4*)in)[i];
    bf16x4 o;
    o.x = (__bf16)v.x; o.y = (__bf16)v.y; o.z = (__bf16)v.z; o.w = (__bf16)v.w;
    ((bf16x4*)out)[i] = o;
}

// ---------------- transpose-cast: W[K,N] f32 -> Wt[Npad,K] bf16 ----------------
__global__ __launch_bounds__(256) void transpose_cast(const float* __restrict__ W,
                                                      __bf16* __restrict__ Wt,
                                                      int Kdim, int Ndim, int Npad) {
    __shared__ float tile[32][33];
    const int n0 = blockIdx.x * 32, k0 = blockIdx.y * 32;
    const int tx = threadIdx.x & 31, ty = threadIdx.x >> 5;
#pragma unroll
    for (int i = 0; i < 32; i += 8) {
        float v = 0.f;
        if (n0 + tx < Ndim) v = W[(size_t)(k0 + ty + i) * Ndim + n0 + tx];
        tile[ty + i][tx] = v;
    }
    __syncthreads();
#pragma unroll
    for (int i = 0; i < 32; i += 8) {
        const int n = n0 + ty + i;
        if (n < Npad) Wt[(size_t)n * Kdim + k0 + tx] = (__bf16)tile[tx][ty + i];
    }
}

// ---------------- depthwise causal conv + gate weights (vectorized) ----------
__global__ __launch_bounds__(256) void conv_pw(const float* __restrict__ z_mem,
                                               const float* __restrict__ conv_k,
                                               const float* __restrict__ score_scale,
                                               const float* __restrict__ decay_slopes,
                                               const float* __restrict__ anchor_slopes,
                                               float* __restrict__ k_val,
                                               float* __restrict__ p_w) {
    const int bl = blockIdx.x;
    const int l = bl & (L_SEQ - 1);
    const int b = bl >> 11;
    const int t = threadIdx.x;

    // main 1024 channels: 4 per thread
    {
        const int c = 4 * t;
        float4 acc = {0.f, 0.f, 0.f, 0.f};
#pragma unroll
        for (int s = 0; s < KS; s++) {
            const int tl = l - (KS - 1) + s;
            if (tl >= 0) {
                const float4 ck = *(const float4*)&conv_k[s * DIM_MEM + c];
                const float4 zv = *(const float4*)&z_mem[((size_t)b * L_SEQ + tl) * DIM_MEM + c];
                acc.x = fmaf(ck.x, zv.x, acc.x);
                acc.y = fmaf(ck.y, zv.y, acc.y);
                acc.z = fmaf(ck.z, zv.z, acc.z);
                acc.w = fmaf(ck.w, zv.w, acc.w);
            }
        }
        *(float4*)&k_val[(size_t)bl * DIM_K + c] = acc;
    }

    // gate channels 1024..1055 -> p_w (threads 0..7, 4 k's each)
    if (t < 8) {
        const int c = DIM_K + 4 * t;
        float acc[4] = {0.f, 0.f, 0.f, 0.f};
#pragma unroll
        for (int s = 0; s < KS; s++) {
            const int tl = l - (KS - 1) + s;
            if (tl >= 0) {
                const float4 ck = *(const float4*)&conv_k[s * DIM_MEM + c];
                const float4 zv = *(const float4*)&z_mem[((size_t)b * L_SEQ + tl) * DIM_MEM + c];
                acc[0] = fmaf(ck.x, zv.x, acc[0]);
                acc[1] = fmaf(ck.y, zv.y, acc[1]);
                acc[2] = fmaf(ck.z, zv.z, acc[2]);
                acc[3] = fmaf(ck.w, zv.w, acc[3]);
            }
        }
#pragma unroll
        for (int j = 0; j < 4; j++) {
            const int k = 4 * t + j;
            const float lp = fminf(fmaxf(score_scale[k] * acc[j], -20.f), 20.f);
            float lt;
            if (k < N_DECAY) {
                const float sd = log1pf(__expf(decay_slopes[k]));
                lt = -sd * (float)(L_SEQ - 1 - l);
            } else {
                const float sa = log1pf(__expf(anchor_slopes[k - N_DECAY]));
                lt = -sa * (float)l;
            }
            p_w[(size_t)bl * K_TOT + k] = __expf(lp + lt);
        }
    }
}

// ---------------- phase 1: per-chunk totals (rotation over m) ----------------
__global__ __launch_bounds__(256) void chunk_sums(const float* __restrict__ k_val,
                                                  const float* __restrict__ p_w,
                                                  const float* __restrict__ theta,
                                                  float* __restrict__ csum,
                                                  float* __restrict__ cden) {
    const int idx = blockIdx.x;
    const int c = idx & (NCHUNK - 1);
    const int bkg = idx / NCHUNK;
    const int kg = bkg & (KG_CNT - 1);
    const int b = bkg / KG_CNT;
    const int t = threadIdx.x;
    const int kl = t >> 5;
    const int h = t & 31;
    const int k = kg * 8 + kl;
    const int bk = b * K_TOT + k;

    const float A0 = theta[(k * H_DIM + h) * M_DIM + 0];
    const float Dt = theta[(k * H_DIM + h) * M_DIM + 1] - A0;

    float nre[M_DIM] = {}, nim[M_DIM] = {};
    float den = 0.f;
    const int l0 = c * CHUNK_L;
#pragma unroll 2
    for (int i = 0; i < CHUNK_L; i++) {
        const size_t bl = (size_t)b * L_SEQ + (l0 + i);
        const float p  = p_w[bl * K_TOT + k];
        const float kv = k_val[bl * DIM_K + k * H_DIM + h];
        float cc = __cosf(kv * A0), ss = __sinf(kv * A0);
        const float cd = __cosf(kv * Dt), sd = __sinf(kv * Dt);
#pragma unroll
        for (int m = 0; m < M_DIM; m++) {
            nre[m] = fmaf(p, cc, nre[m]);
            nim[m] = fmaf(p, ss, nim[m]);
            const float c2 = fmaf(cc, cd, -(ss * sd));
            ss = fmaf(ss, cd, cc * sd);
            cc = c2;
        }
        den += p;
    }

    float* base = &csum[(((size_t)bk * NCHUNK + c) * 256 + h * M_DIM) * 2];
#pragma unroll
    for (int j = 0; j < 4; j++) {
        f32x4 v = { nre[2 * j], nim[2 * j], nre[2 * j + 1], nim[2 * j + 1] };
        ((f32x4*)base)[j] = v;
    }
    if (h == 0) cden[bk * NCHUNK + c] = den;
}

// ---------------- phase 2: exclusive prefix over chunks ----------------
__global__ __launch_bounds__(256) void chunk_prefix(float* __restrict__ csum,
                                                    float* __restrict__ cden) {
    const int bk = blockIdx.x;
    const int t = threadIdx.x;

    if (t < 64) {
        const float orig = cden[bk * NCHUNK + t];
        float v = orig;
#pragma unroll
        for (int d = 1; d < 64; d <<= 1) {
            const float u = __shfl_up(v, d);
            if (t >= d) v += u;
        }
        cden[bk * NCHUNK + t] = v - orig;
    }

    float run_re = 0.f, run_im = 0.f;
    for (int c = 0; c < NCHUNK; c++) {
        float2* p = (float2*)&csum[(((size_t)bk * NCHUNK + c) * 256 + t) * 2];
        const float2 v = *p;
        *p = make_float2(run_re, run_im);
        run_re += v.x;
        run_im += v.y;
    }
}

// ---------------- phase 3: replay + output epilogue ----------------
__global__ __launch_bounds__(256) void scan_out(const __bf16* __restrict__ q_b,
                                                const float* __restrict__ k_val,
                                                const float* __restrict__ p_w,
                                                const float* __restrict__ theta,
                                                const float* __restrict__ csum,
                                                const float* __restrict__ cden,
                                                const float* __restrict__ W_re,
                                                const float* __restrict__ W_im,
                                                const float* __restrict__ norm_scale,
                                                __bf16* __restrict__ y) {
    const int idx = blockIdx.x;
    const int c = idx & (NCHUNK - 1);
    const int bkg = idx / NCHUNK;
    const int kg = bkg & (KG_CNT - 1);
    const int b = bkg / KG_CNT;
    const int t = threadIdx.x;
    const int kl = t >> 5;
    const int h = t & 31;
    const int k = kg * 8 + kl;
    const int bk = b * K_TOT + k;

    const float A0 = theta[(k * H_DIM + h) * M_DIM + 0];
    const float Dt = theta[(k * H_DIM + h) * M_DIM + 1] - A0;

    float nre[M_DIM], nim[M_DIM];
    {
        const float* base = &csum[(((size_t)bk * NCHUNK + c) * 256 + h * M_DIM) * 2];
#pragma unroll
        for (int j = 0; j < 4; j++) {
            const f32x4 v = ((const f32x4*)base)[j];
            nre[2 * j] = v.x; nim[2 * j] = v.y;
            nre[2 * j + 1] = v.z; nim[2 * j + 1] = v.w;
        }
    }
    float den = cden[bk * NCHUNK + c];

    const float wsc_re = norm_scale[h] * W_re[h * H_DIM + h];
    const float wsc_im = norm_scale[H_DIM + h] * W_im[h * H_DIM + h];

    const int l0 = c * CHUNK_L;
    for (int i = 0; i < CHUNK_L; i++) {
        const size_t bl = (size_t)b * L_SEQ + (l0 + i);
        const float p  = p_w[bl * K_TOT + k];
        const float kv = k_val[bl * DIM_K + k * H_DIM + h];

        const __bf16* qp = &q_b[bl * DIM_Q + (size_t)(kg * H_DIM + h) * 16];
        const bf16x8 q0 = *(const bf16x8*)qp;
        const bf16x8 q1 = *(const bf16x8*)(qp + 8);

        float cc = __cosf(kv * A0), ss = __sinf(kv * A0);
        const float cd = __cosf(kv * Dt), sd = __sinf(kv * Dt);

        float ore = 0.f, oim = 0.f;
#pragma unroll
        for (int m = 0; m < M_DIM; m++) {
            nre[m] = fmaf(p, cc, nre[m]);
            nim[m] = fmaf(p, ss, nim[m]);
            const float qr = (m < 4) ? (float)q0[2 * (m & 3)]     : (float)q1[2 * (m & 3)];
            const float qi = (m < 4) ? (float)q0[2 * (m & 3) + 1] : (float)q1[2 * (m & 3) + 1];
            ore = fmaf(nre[m], qr, fmaf(nim[m], qi, ore));
            oim = fmaf(nim[m], qr, fmaf(-nre[m], qi, oim));
            const float c2 = fmaf(cc, cd, -(ss * sd));
            ss = fmaf(ss, cd, cc * sd);
            cc = c2;
        }
        den += p;
        const float inv = __builtin_amdgcn_rcpf(fmaxf(den, 1e-4f));

        const float v = (ore * wsc_re + oim * wsc_im) * inv;
        const float yv = v * __builtin_amdgcn_rcpf(1.0f + __expf(-v));
        y[bl * DIM_K + k * H_DIM + h] = (__bf16)yv;
    }
}

// ---------------- launch ----------------
extern "C" void kernel_launch(void* const* d_in, const int* in_sizes, int n_in,
                              void* d_out, int out_size, void* d_ws, size_t ws_size,
                              hipStream_t stream) {
    const float* x            = (const float*)d_in[0];
    const float* W_in         = (const float*)d_in[1];
    const float* conv_k       = (const float*)d_in[2];
    const float* theta        = (const float*)d_in[3];
    const float* decay_slopes = (const float*)d_in[4];
    const float* anchor_slopes= (const float*)d_in[5];
    const float* score_scale  = (const float*)d_in[6];
    const float* W_re         = (const float*)d_in[7];
    const float* W_im         = (const float*)d_in[8];
    const float* norm_scale   = (const float*)d_in[9];
    const float* W_out        = (const float*)d_in[10];
    float* out = (float*)d_out;

    float* ws = (float*)d_ws;
    size_t off = 0;
    float* z_mem  = ws + off; off += (size_t)BL_TOT * DIM_MEM;                // 4.33M
    float* k_val  = ws + off; off += (size_t)BL_TOT * DIM_K;                  // 4.19M
    float* p_w    = ws + off; off += (size_t)BL_TOT * K_TOT;
    float* csum   = ws + off; off += (size_t)B_SZ * K_TOT * NCHUNK * 256 * 2;
    float* cden   = ws + off; off += (size_t)B_SZ * K_TOT * NCHUNK;
    __bf16* x_b     = (__bf16*)(ws + off); off += (size_t)BL_TOT * D_MODEL / 2;
    __bf16* W_in_T  = (__bf16*)(ws + off); off += (size_t)NPAD_IN * D_MODEL / 2;
    __bf16* W_out_T = (__bf16*)(ws + off); off += (size_t)D_MODEL * D_MODEL / 2;
    __bf16* y_b     = (__bf16*)(ws + off); off += (size_t)BL_TOT * DIM_K / 2;
    __bf16* q_b     = (__bf16*)(ws + off); off += (size_t)BL_TOT * DIM_Q / 2;

    cast_bf16<<<(BL_TOT * D_MODEL / 4 + 255) / 256, 256, 0, stream>>>(
        x, x_b, BL_TOT * D_MODEL / 4);
    {
        dim3 g(NPAD_IN / 32, D_MODEL / 32);
        transpose_cast<<<g, 256, 0, stream>>>(W_in, W_in_T, D_MODEL, TOTAL_DIM, NPAD_IN);
    }
    {
        dim3 g(D_MODEL / 32, D_MODEL / 32);
        transpose_cast<<<g, 256, 0, stream>>>(W_out, W_out_T, D_MODEL, D_MODEL, D_MODEL);
    }

    // 1) z = x @ W_in (split epilogue: z_mem f32 + q_b bf16)
    gemm_bf16<1><<<(NPAD_IN / 128) * (BL_TOT / 128), 256, 0, stream>>>(
        x_b, W_in_T, z_mem, q_b, NPAD_IN, D_MODEL, NPAD_IN / 128);

    // 2) depthwise conv + p_w
    conv_pw<<<BL_TOT, 256, 0, stream>>>(z_mem, conv_k, score_scale, decay_slopes,
                                        anchor_slopes, k_val, p_w);
    // 3) blocked scan
    chunk_sums<<<B_SZ * KG_CNT * NCHUNK, 256, 0, stream>>>(k_val, p_w, theta, csum, cden);
    chunk_prefix<<<B_SZ * K_TOT, 256, 0, stream>>>(csum, cden);
    scan_out<<<B_SZ * KG_CNT * NCHUNK, 256, 0, stream>>>(q_b, k_val, p_w, theta, csum,
                                                         cden, W_re, W_im, norm_scale, y_b);
    // 4) out = y @ W_out
    gemm_bf16<0><<<(D_MODEL / 128) * (BL_TOT / 128), 256, 0, stream>>>(
        y_b, W_out_T, out, nullptr, D_MODEL, D_MODEL, D_MODEL / 128);
}

// Round 5
// 133.569 us; speedup vs baseline: 6.9955x; 1.0808x over previous
//
#include <hip/hip_runtime.h>
#include <hip/hip_bf16.h>
#include <math.h>

// ---------------- problem constants ----------------
#define D_MODEL   1024
#define K_TOT     32
#define N_DECAY   28
#define M_DIM     8
#define KS        4
#define H_DIM     32
#define DIM_K     1024
#define DIM_MEM   1056
#define DIM_Q     2048
#define TOTAL_DIM 3104
#define NPAD_IN   3328          // 13 * 256
#define B_SZ      2
#define L_SEQ     2048
#define BL_TOT    4096

#define KG_CNT    4             // k-groups of 8
#define NCHUNK    64
#define CHUNK_L   32            // L_SEQ / NCHUNK

typedef __attribute__((ext_vector_type(8))) __bf16 bf16x8;
typedef __attribute__((ext_vector_type(4))) __bf16 bf16x4;
typedef __attribute__((ext_vector_type(4))) float  f32x4;

__device__ __forceinline__ void gload_lds16(const void* g, void* l) {
    __builtin_amdgcn_global_load_lds(
        (const __attribute__((address_space(1))) void*)g,
        (__attribute__((address_space(3))) void*)l, 16, 0, 0);
}

// ================= big-tile deep-pipeline GEMM (GEMM1) ======================
// C[M,Npad] = A[M,K] * Bt[Npad,K]; BM=BN=256, BK=64, 512 thr (8 waves 2x4),
// double-buffered LDS (128 KiB), 2-tile-ahead prefetch, counted vmcnt.
// EPI=1 split epilogue: col<1056 -> f32 z_mem, [1056,3104) -> bf16 q_b.
__global__ __launch_bounds__(512, 1) void gemm_big(const __bf16* __restrict__ A,
                                                   const __bf16* __restrict__ Bt,
                                                   float* __restrict__ C,
                                                   __bf16* __restrict__ Cq,
                                                   int Kdim, int gx) {
    __shared__ __bf16 lds[2][2][256 * 64];   // [buf][A=0/B=1]

    const int tid  = threadIdx.x;
    const int w    = tid >> 6;              // 0..7
    const int lane = tid & 63;
    const int l15  = lane & 15;
    const int l16  = lane >> 4;
    const int wm   = w >> 2;                // 0..1
    const int wn   = w & 3;                 // 0..3

    // XCD-chunked bijective swizzle (nwg % 8 == 0)
    const int nwg = gridDim.x;
    int lin = blockIdx.x;
    lin = (lin & 7) * (nwg >> 3) + (lin >> 3);
    const int bx = lin % gx, by = lin / gx;
    const int r0 = by * 256, c0 = bx * 256;

    const int srow  = w * 8 + (lane >> 3);  // row within 64-row group
    const int sslot = lane & 7;             // 16B slot in 128B row

    f32x4 acc[8][4] = {};

    const int NT = Kdim / 64;               // 16

#define STAGE(T, BUF)                                                          \
    {                                                                          \
        const int k0_ = (T) * 64;                                              \
        _Pragma("unroll")                                                      \
        for (int j = 0; j < 4; j++) {                                          \
            const int r  = j * 64 + srow;                                      \
            const int so = sslot ^ (r & 7);                                    \
            gload_lds16(A + (size_t)(r0 + r) * Kdim + k0_ + so * 8,            \
                        &lds[BUF][0][(j * 64 + w * 8) * 64]);                  \
        }                                                                      \
        _Pragma("unroll")                                                      \
        for (int j = 0; j < 4; j++) {                                          \
            const int r  = j * 64 + srow;                                      \
            const int so = sslot ^ (r & 7);                                    \
            gload_lds16(Bt + (size_t)(c0 + r) * Kdim + k0_ + so * 8,           \
                        &lds[BUF][1][(j * 64 + w * 8) * 64]);                  \
        }                                                                      \
    }

    // prologue: tiles 0 and 1 in flight
    STAGE(0, 0);
    STAGE(1, 1);
    __builtin_amdgcn_sched_barrier(0);
    asm volatile("s_waitcnt vmcnt(8)" ::: "memory");   // tile0 landed
    __builtin_amdgcn_s_barrier();
    __builtin_amdgcn_sched_barrier(0);

    for (int t = 0; t < NT; ++t) {
        const int cur = t & 1;
#pragma unroll
        for (int kk = 0; kk < 2; kk++) {
            bf16x8 b[4];
#pragma unroll
            for (int ni = 0; ni < 4; ni++) {
                const int col  = wn * 64 + ni * 16 + l15;
                const int slot = (kk * 4 + l16) ^ (col & 7);
                b[ni] = *(const bf16x8*)&lds[cur][1][col * 64 + slot * 8];
            }
            bf16x8 a[8];
#pragma unroll
            for (int mi = 0; mi < 8; mi++) {
                const int row  = wm * 128 + mi * 16 + l15;
                const int slot = (kk * 4 + l16) ^ (row & 7);
                a[mi] = *(const bf16x8*)&lds[cur][0][row * 64 + slot * 8];
            }
            __builtin_amdgcn_s_setprio(1);
#pragma unroll
            for (int mi = 0; mi < 8; mi++)
#pragma unroll
                for (int ni = 0; ni < 4; ni++)
                    acc[mi][ni] = __builtin_amdgcn_mfma_f32_16x16x32_bf16(
                        a[mi], b[ni], acc[mi][ni], 0, 0, 0);
            __builtin_amdgcn_s_setprio(0);
        }
        // sync cluster: reads-done barrier, prefetch t+2, counted wait, ready barrier
        __builtin_amdgcn_sched_barrier(0);
        __builtin_amdgcn_s_barrier();
        __builtin_amdgcn_sched_barrier(0);
        if (t + 2 < NT) {
            STAGE(t + 2, cur);
            __builtin_amdgcn_sched_barrier(0);
            asm volatile("s_waitcnt vmcnt(8)" ::: "memory");  // t+1 landed
        } else {
            asm volatile("s_waitcnt vmcnt(0)" ::: "memory");
        }
        __builtin_amdgcn_s_barrier();
        __builtin_amdgcn_sched_barrier(0);
    }
#undef STAGE

    // epilogue: C/D layout col=lane&15, row=(lane>>4)*4+q
#pragma unroll
    for (int mi = 0; mi < 8; mi++) {
#pragma unroll
        for (int ni = 0; ni < 4; ni++) {
            const int col = c0 + wn * 64 + ni * 16 + l15;
            const int row = r0 + wm * 128 + mi * 16 + l16 * 4;
            if (col < DIM_MEM) {
#pragma unroll
                for (int q = 0; q < 4; q++)
                    C[(size_t)(row + q) * DIM_MEM + col] = acc[mi][ni][q];
            } else if (col < TOTAL_DIM) {
#pragma unroll
                for (int q = 0; q < 4; q++)
                    Cq[(size_t)(row + q) * DIM_Q + (col - DIM_MEM)] =
                        (__bf16)acc[mi][ni][q];
            }
        }
    }
}

// ================= 128-tile GEMM (GEMM2), m97 structure =====================
__global__ __launch_bounds__(256) void gemm128(const __bf16* __restrict__ A,
                                               const __bf16* __restrict__ Bt,
                                               float* __restrict__ C,
                                               int Ndim, int Kdim, int gx) {
    __shared__ __bf16 As[128 * 64];
    __shared__ __bf16 Bs[128 * 64];

    const int nwg = gridDim.x;
    int lin = blockIdx.x;
    lin = (lin & 7) * (nwg >> 3) + (lin >> 3);
    const int bx = lin % gx, by = lin / gx;
    const int r0 = by * 128, col0 = bx * 128;

    const int tid  = threadIdx.x;
    const int w    = tid >> 6;
    const int lane = tid & 63;
    const int l15  = lane & 15;
    const int l16  = lane >> 4;
    const int wm   = w >> 1, wn = w & 1;

    const int srow  = w * 8 + (lane >> 3);
    const int sslot = lane & 7;

    f32x4 acc[4][4] = {};

    for (int k0 = 0; k0 < Kdim; k0 += 64) {
#pragma unroll
        for (int j = 0; j < 4; j++) {
            const int r  = j * 32 + srow;
            const int so = sslot ^ (r & 7);
            gload_lds16(A + (size_t)(r0 + r) * Kdim + k0 + so * 8,
                        &As[(j * 32 + w * 8) * 64]);
        }
#pragma unroll
        for (int j = 0; j < 4; j++) {
            const int r  = j * 32 + srow;
            const int so = sslot ^ (r & 7);
            gload_lds16(Bt + (size_t)(col0 + r) * Kdim + k0 + so * 8,
                        &Bs[(j * 32 + w * 8) * 64]);
        }
        __syncthreads();

#pragma unroll
        for (int kk = 0; kk < 2; kk++) {
            bf16x8 a[4], b[4];
#pragma unroll
            for (int mi = 0; mi < 4; mi++) {
                const int row  = wm * 64 + mi * 16 + l15;
                const int slot = (kk * 4 + l16) ^ (row & 7);
                a[mi] = *(const bf16x8*)&As[row * 64 + slot * 8];
            }
#pragma unroll
            for (int ni = 0; ni < 4; ni++) {
                const int col  = wn * 64 + ni * 16 + l15;
                const int slot = (kk * 4 + l16) ^ (col & 7);
                b[ni] = *(const bf16x8*)&Bs[col * 64 + slot * 8];
            }
#pragma unroll
            for (int mi = 0; mi < 4; mi++)
#pragma unroll
                for (int ni = 0; ni < 4; ni++)
                    acc[mi][ni] = __builtin_amdgcn_mfma_f32_16x16x32_bf16(
                        a[mi], b[ni], acc[mi][ni], 0, 0, 0);
        }
        __syncthreads();
    }

#pragma unroll
    for (int mi = 0; mi < 4; mi++) {
#pragma unroll
        for (int ni = 0; ni < 4; ni++) {
            const int col = col0 + wn * 64 + ni * 16 + l15;
            const int row = r0 + wm * 64 + mi * 16 + l16 * 4;
#pragma unroll
            for (int q = 0; q < 4; q++)
                C[(size_t)(row + q) * Ndim + col] = acc[mi][ni][q];
        }
    }
}

// ---------------- straight cast fp32 -> bf16 ----------------
__global__ __launch_bounds__(256) void cast_bf16(const float* __restrict__ in,
                                                 __bf16* __restrict__ out, int n4) {
    const int i = blockIdx.x * blockDim.x + threadIdx.x;
    if (i >= n4) return;
    const float4 v = ((const float4*)in)[i];
    bf16x4 o;
    o.x = (__bf16)v.x; o.y = (__bf16)v.y; o.z = (__bf16)v.z; o.w = (__bf16)v.w;
    ((bf16x4*)out)[i] = o;
}

// ---------------- transpose-cast: W[K,N] f32 -> Wt[Npad,K] bf16 ----------------
__global__ __launch_bounds__(256) void transpose_cast(const float* __restrict__ W,
                                                      __bf16* __restrict__ Wt,
                                                      int Kdim, int Ndim, int Npad) {
    __shared__ float tile[32][33];
    const int n0 = blockIdx.x * 32, k0 = blockIdx.y * 32;
    const int tx = threadIdx.x & 31, ty = threadIdx.x >> 5;
#pragma unroll
    for (int i = 0; i < 32; i += 8) {
        float v = 0.f;
        if (n0 + tx < Ndim) v = W[(size_t)(k0 + ty + i) * Ndim + n0 + tx];
        tile[ty + i][tx] = v;
    }
    __syncthreads();
#pragma unroll
    for (int i = 0; i < 32; i += 8) {
        const int n = n0 + ty + i;
        if (n < Npad) Wt[(size_t)n * Kdim + k0 + tx] = (__bf16)tile[tx][ty + i];
    }
}

// ---------------- depthwise causal conv + gate weights ----------------
__global__ __launch_bounds__(256) void conv_pw(const float* __restrict__ z_mem,
                                               const float* __restrict__ conv_k,
                                               const float* __restrict__ score_scale,
                                               const float* __restrict__ decay_slopes,
                                               const float* __restrict__ anchor_slopes,
                                               __bf16* __restrict__ k_val,
                                               float* __restrict__ p_w) {
    const int bl = blockIdx.x;
    const int l = bl & (L_SEQ - 1);
    const int b = bl >> 11;
    const int t = threadIdx.x;

    {
        const int c = 4 * t;
        float4 acc = {0.f, 0.f, 0.f, 0.f};
#pragma unroll
        for (int s = 0; s < KS; s++) {
            const int tl = l - (KS - 1) + s;
            if (tl >= 0) {
                const float4 ck = *(const float4*)&conv_k[s * DIM_MEM + c];
                const float4 zv = *(const float4*)&z_mem[((size_t)b * L_SEQ + tl) * DIM_MEM + c];
                acc.x = fmaf(ck.x, zv.x, acc.x);
                acc.y = fmaf(ck.y, zv.y, acc.y);
                acc.z = fmaf(ck.z, zv.z, acc.z);
                acc.w = fmaf(ck.w, zv.w, acc.w);
            }
        }
        bf16x4 o;
        o.x = (__bf16)acc.x; o.y = (__bf16)acc.y;
        o.z = (__bf16)acc.z; o.w = (__bf16)acc.w;
        *(bf16x4*)&k_val[(size_t)bl * DIM_K + c] = o;
    }

    if (t < 8) {
        const int c = DIM_MEM - K_TOT + 4 * t;
        float acc[4] = {0.f, 0.f, 0.f, 0.f};
#pragma unroll
        for (int s = 0; s < KS; s++) {
            const int tl = l - (KS - 1) + s;
            if (tl >= 0) {
                const float4 ck = *(const float4*)&conv_k[s * DIM_MEM + c];
                const float4 zv = *(const float4*)&z_mem[((size_t)b * L_SEQ + tl) * DIM_MEM + c];
                acc[0] = fmaf(ck.x, zv.x, acc[0]);
                acc[1] = fmaf(ck.y, zv.y, acc[1]);
                acc[2] = fmaf(ck.z, zv.z, acc[2]);
                acc[3] = fmaf(ck.w, zv.w, acc[3]);
            }
        }
#pragma unroll
        for (int j = 0; j < 4; j++) {
            const int k = 4 * t + j;
            const float lp = fminf(fmaxf(score_scale[k] * acc[j], -20.f), 20.f);
            float lt;
            if (k < N_DECAY) {
                const float sd = log1pf(__expf(decay_slopes[k]));
                lt = -sd * (float)(L_SEQ - 1 - l);
            } else {
                const float sa = log1pf(__expf(anchor_slopes[k - N_DECAY]));
                lt = -sa * (float)l;
            }
            p_w[(size_t)bl * K_TOT + k] = __expf(lp + lt);
        }
    }
}

// ---------------- phase 1: per-chunk totals (rotation over m) ----------------
__global__ __launch_bounds__(256) void chunk_sums(const __bf16* __restrict__ k_val,
                                                  const float* __restrict__ p_w,
                                                  const float* __restrict__ theta,
                                                  float* __restrict__ csum,
                                                  float* __restrict__ cden) {
    const int idx = blockIdx.x;
    const int c = idx & (NCHUNK - 1);
    const int bkg = idx / NCHUNK;
    const int kg = bkg & (KG_CNT - 1);
    const int b = bkg / KG_CNT;
    const int t = threadIdx.x;
    const int kl = t >> 5;
    const int h = t & 31;
    const int k = kg * 8 + kl;
    const int bk = b * K_TOT + k;

    const float A0 = theta[(k * H_DIM + h) * M_DIM + 0];
    const float Dt = theta[(k * H_DIM + h) * M_DIM + 1] - A0;

    float nre[M_DIM] = {}, nim[M_DIM] = {};
    float den = 0.f;
    const int l0 = c * CHUNK_L;
#pragma unroll 2
    for (int i = 0; i < CHUNK_L; i++) {
        const size_t bl = (size_t)b * L_SEQ + (l0 + i);
        const float p  = p_w[bl * K_TOT + k];
        const float kv = (float)k_val[bl * DIM_K + k * H_DIM + h];
        float cc = __cosf(kv * A0), ss = __sinf(kv * A0);
        const float cd = __cosf(kv * Dt), sd = __sinf(kv * Dt);
#pragma unroll
        for (int m = 0; m < M_DIM; m++) {
            nre[m] = fmaf(p, cc, nre[m]);
            nim[m] = fmaf(p, ss, nim[m]);
            const float c2 = fmaf(cc, cd, -(ss * sd));
            ss = fmaf(ss, cd, cc * sd);
            cc = c2;
        }
        den += p;
    }

    float* base = &csum[(((size_t)bk * NCHUNK + c) * 256 + h * M_DIM) * 2];
#pragma unroll
    for (int j = 0; j < 4; j++) {
        f32x4 v = { nre[2 * j], nim[2 * j], nre[2 * j + 1], nim[2 * j + 1] };
        ((f32x4*)base)[j] = v;
    }
    if (h == 0) cden[bk * NCHUNK + c] = den;
}

// ---------------- phase 2: exclusive prefix over chunks ----------------
__global__ __launch_bounds__(256) void chunk_prefix(float* __restrict__ csum,
                                                    float* __restrict__ cden) {
    const int bk = blockIdx.x;
    const int t = threadIdx.x;

    if (t < 64) {
        const float orig = cden[bk * NCHUNK + t];
        float v = orig;
#pragma unroll
        for (int d = 1; d < 64; d <<= 1) {
            const float u = __shfl_up(v, d);
            if (t >= d) v += u;
        }
        cden[bk * NCHUNK + t] = v - orig;
    }

    float run_re = 0.f, run_im = 0.f;
    for (int c = 0; c < NCHUNK; c++) {
        float2* p = (float2*)&csum[(((size_t)bk * NCHUNK + c) * 256 + t) * 2];
        const float2 v = *p;
        *p = make_float2(run_re, run_im);
        run_re += v.x;
        run_im += v.y;
    }
}

// ---------------- phase 3: replay + output epilogue ----------------
__global__ __launch_bounds__(256) void scan_out(const __bf16* __restrict__ q_b,
                                                const __bf16* __restrict__ k_val,
                                                const float* __restrict__ p_w,
                                                const float* __restrict__ theta,
                                                const float* __restrict__ csum,
                                                const float* __restrict__ cden,
                                                const float* __restrict__ W_re,
                                                const float* __restrict__ W_im,
                                                const float* __restrict__ norm_scale,
                                                __bf16* __restrict__ y) {
    const int idx = blockIdx.x;
    const int c = idx & (NCHUNK - 1);
    const int bkg = idx / NCHUNK;
    const int kg = bkg & (KG_CNT - 1);
    const int b = bkg / KG_CNT;
    const int t = threadIdx.x;
    const int kl = t >> 5;
    const int h = t & 31;
    const int k = kg * 8 + kl;
    const int bk = b * K_TOT + k;

    const float A0 = theta[(k * H_DIM + h) * M_DIM + 0];
    const float Dt = theta[(k * H_DIM + h) * M_DIM + 1] - A0;

    float nre[M_DIM], nim[M_DIM];
    {
        const float* base = &csum[(((size_t)bk * NCHUNK + c) * 256 + h * M_DIM) * 2];
#pragma unroll
        for (int j = 0; j < 4; j++) {
            const f32x4 v = ((const f32x4*)base)[j];
            nre[2 * j] = v.x; nim[2 * j] = v.y;
            nre[2 * j + 1] = v.z; nim[2 * j + 1] = v.w;
        }
    }
    float den = cden[bk * NCHUNK + c];

    const float wsc_re = norm_scale[h] * W_re[h * H_DIM + h];
    const float wsc_im = norm_scale[H_DIM + h] * W_im[h * H_DIM + h];

    const int l0 = c * CHUNK_L;
    for (int i = 0; i < CHUNK_L; i++) {
        const size_t bl = (size_t)b * L_SEQ + (l0 + i);
        const float p  = p_w[bl * K_TOT + k];
        const float kv = (float)k_val[bl * DIM_K + k * H_DIM + h];

        const __bf16* qp = &q_b[bl * DIM_Q + (size_t)(kg * H_DIM + h) * 16];
        const bf16x8 q0 = *(const bf16x8*)qp;
        const bf16x8 q1 = *(const bf16x8*)(qp + 8);

        float cc = __cosf(kv * A0), ss = __sinf(kv * A0);
        const float cd = __cosf(kv * Dt), sd = __sinf(kv * Dt);

        float ore = 0.f, oim = 0.f;
#pragma unroll
        for (int m = 0; m < M_DIM; m++) {
            nre[m] = fmaf(p, cc, nre[m]);
            nim[m] = fmaf(p, ss, nim[m]);
            const float qr = (m < 4) ? (float)q0[2 * (m & 3)]     : (float)q1[2 * (m & 3)];
            const float qi = (m < 4) ? (float)q0[2 * (m & 3) + 1] : (float)q1[2 * (m & 3) + 1];
            ore = fmaf(nre[m], qr, fmaf(nim[m], qi, ore));
            oim = fmaf(nim[m], qr, fmaf(-nre[m], qi, oim));
            const float c2 = fmaf(cc, cd, -(ss * sd));
            ss = fmaf(ss, cd, cc * sd);
            cc = c2;
        }
        den += p;
        const float inv = __builtin_amdgcn_rcpf(fmaxf(den, 1e-4f));

        const float v = (ore * wsc_re + oim * wsc_im) * inv;
        const float yv = v * __builtin_amdgcn_rcpf(1.0f + __expf(-v));
        y[bl * DIM_K + k * H_DIM + h] = (__bf16)yv;
    }
}

// ---------------- launch ----------------
extern "C" void kernel_launch(void* const* d_in, const int* in_sizes, int n_in,
                              void* d_out, int out_size, void* d_ws, size_t ws_size,
                              hipStream_t stream) {
    const float* x            = (const float*)d_in[0];
    const float* W_in         = (const float*)d_in[1];
    const float* conv_k       = (const float*)d_in[2];
    const float* theta        = (const float*)d_in[3];
    const float* decay_slopes = (const float*)d_in[4];
    const float* anchor_slopes= (const float*)d_in[5];
    const float* score_scale  = (const float*)d_in[6];
    const float* W_re         = (const float*)d_in[7];
    const float* W_im         = (const float*)d_in[8];
    const float* norm_scale   = (const float*)d_in[9];
    const float* W_out        = (const float*)d_in[10];
    float* out = (float*)d_out;

    float* ws = (float*)d_ws;
    size_t off = 0;
    float* z_mem  = ws + off; off += (size_t)BL_TOT * DIM_MEM;
    float* p_w    = ws + off; off += (size_t)BL_TOT * K_TOT;
    float* csum   = ws + off; off += (size_t)B_SZ * K_TOT * NCHUNK * 256 * 2;
    float* cden   = ws + off; off += (size_t)B_SZ * K_TOT * NCHUNK;
    __bf16* k_val   = (__bf16*)(ws + off); off += (size_t)BL_TOT * DIM_K / 2;
    __bf16* x_b     = (__bf16*)(ws + off); off += (size_t)BL_TOT * D_MODEL / 2;
    __bf16* W_in_T  = (__bf16*)(ws + off); off += (size_t)NPAD_IN * D_MODEL / 2;
    __bf16* W_out_T = (__bf16*)(ws + off); off += (size_t)D_MODEL * D_MODEL / 2;
    __bf16* y_b     = (__bf16*)(ws + off); off += (size_t)BL_TOT * DIM_K / 2;
    __bf16* q_b     = (__bf16*)(ws + off); off += (size_t)BL_TOT * DIM_Q / 2;

    cast_bf16<<<(BL_TOT * D_MODEL / 4 + 255) / 256, 256, 0, stream>>>(
        x, x_b, BL_TOT * D_MODEL / 4);
    {
        dim3 g(NPAD_IN / 32, D_MODEL / 32);
        transpose_cast<<<g, 256, 0, stream>>>(W_in, W_in_T, D_MODEL, TOTAL_DIM, NPAD_IN);
    }
    {
        dim3 g(D_MODEL / 32, D_MODEL / 32);
        transpose_cast<<<g, 256, 0, stream>>>(W_out, W_out_T, D_MODEL, D_MODEL, D_MODEL);
    }

    // 1) z = x @ W_in (deep-pipeline 256^2, split epilogue)
    gemm_big<<<(NPAD_IN / 256) * (BL_TOT / 256), 512, 0, stream>>>(
        x_b, W_in_T, z_mem, q_b, D_MODEL, NPAD_IN / 256);

    // 2) depthwise conv + p_w
    conv_pw<<<BL_TOT, 256, 0, stream>>>(z_mem, conv_k, score_scale, decay_slopes,
                                        anchor_slopes, k_val, p_w);
    // 3) blocked scan
    chunk_sums<<<B_SZ * KG_CNT * NCHUNK, 256, 0, stream>>>(k_val, p_w, theta, csum, cden);
    chunk_prefix<<<B_SZ * K_TOT, 256, 0, stream>>>(csum, cden);
    scan_out<<<B_SZ * KG_CNT * NCHUNK, 256, 0, stream>>>(q_b, k_val, p_w, theta, csum,
                                                         cden, W_re, W_im, norm_scale, y_b);
    // 4) out = y @ W_out (128^2)
    gemm128<<<(D_MODEL / 128) * (BL_TOT / 128), 256, 0, stream>>>(
        y_b, W_out_T, out, D_MODEL, D_MODEL, D_MODEL / 128);
}

// Round 6
// 125.842 us; speedup vs baseline: 7.4251x; 1.0614x over previous
//
#include <hip/hip_runtime.h>
#include <hip/hip_bf16.h>
#include <math.h>

// ---------------- problem constants ----------------
#define D_MODEL   1024
#define K_TOT     32
#define N_DECAY   28
#define M_DIM     8
#define KS        4
#define H_DIM     32
#define DIM_K     1024
#define DIM_MEM   1056
#define DIM_Q     2048
#define TOTAL_DIM 3104
#define NPAD_IN   3328          // 13 * 256
#define B_SZ      2
#define L_SEQ     2048
#define BL_TOT    4096

#define KG_CNT    4             // k-groups of 8
#define NCHUNK    64
#define CHUNK_L   32            // L_SEQ / NCHUNK

typedef __attribute__((ext_vector_type(8))) __bf16 bf16x8;
typedef __attribute__((ext_vector_type(4))) __bf16 bf16x4;
typedef __attribute__((ext_vector_type(4))) float  f32x4;

__device__ __forceinline__ void gload_lds16(const void* g, void* l) {
    __builtin_amdgcn_global_load_lds(
        (const __attribute__((address_space(1))) void*)g,
        (__attribute__((address_space(3))) void*)l, 16, 0, 0);
}

// ================= GEMM1: 256^2 tile, 4-phase interleaved pipeline ==========
// C[M,Npad] = A[M,K] * Bt[Npad,K]; BK=64, 512 thr (8 waves 2x4), dbuf LDS,
// 2-tile-ahead prefetch with counted vmcnt (never 0 mid-loop).
// Split epilogue: col<1056 -> f32 z_mem, [1056,3104) -> bf16 q_b.
__global__ __launch_bounds__(512, 2) void gemm_big(const __bf16* __restrict__ A,
                                                   const __bf16* __restrict__ Bt,
                                                   float* __restrict__ C,
                                                   __bf16* __restrict__ Cq,
                                                   int Kdim, int gx) {
    __shared__ __bf16 lds[2][2][256 * 64];   // [buf][A=0/B=1]  128 KiB

    const int tid  = threadIdx.x;
    const int w    = tid >> 6;              // 0..7
    const int lane = tid & 63;
    const int l15  = lane & 15;
    const int l16  = lane >> 4;
    const int wm   = w >> 2;                // 0..1
    const int wn   = w & 3;                 // 0..3

    const int nwg = gridDim.x;
    int lin = blockIdx.x;
    lin = (lin & 7) * (nwg >> 3) + (lin >> 3);
    const int bx = lin % gx, by = lin / gx;
    const int r0 = by * 256, c0 = bx * 256;

    const int srl   = lane >> 3;            // 0..7
    const int sslot = lane & 7;

    f32x4 acc[8][4] = {};
    const int NT = Kdim / 64;               // 16

#define STG_A(T, BUF, J)                                                       \
    {                                                                          \
        const int r_  = (J) * 64 + w * 8 + srl;                                \
        const int so_ = sslot ^ (r_ & 7);                                      \
        gload_lds16(A + (size_t)(r0 + r_) * Kdim + (T) * 64 + so_ * 8,         \
                    &lds[BUF][0][((J) * 64 + w * 8) * 64]);                    \
    }
#define STG_B(T, BUF, J)                                                       \
    {                                                                          \
        const int r_  = (J) * 64 + w * 8 + srl;                                \
        const int so_ = sslot ^ (r_ & 7);                                      \
        gload_lds16(Bt + (size_t)(c0 + r_) * Kdim + (T) * 64 + so_ * 8,        \
                    &lds[BUF][1][((J) * 64 + w * 8) * 64]);                    \
    }

#define LOAD_A(AP, MIBASE)                                                     \
    _Pragma("unroll") for (int m2 = 0; m2 < 2; m2++)                           \
        _Pragma("unroll") for (int kk = 0; kk < 2; kk++) {                     \
            const int row_  = wm * 128 + ((MIBASE) + m2) * 16 + l15;           \
            const int slot_ = (kk * 4 + l16) ^ (row_ & 7);                     \
            AP[m2][kk] = *(const bf16x8*)&As_[row_ * 64 + slot_ * 8];          \
        }

#define PHASE(AP, MIBASE)                                                      \
    __builtin_amdgcn_s_barrier();                                              \
    asm volatile("s_waitcnt lgkmcnt(0)" ::: "memory");                         \
    __builtin_amdgcn_sched_barrier(0);                                         \
    __builtin_amdgcn_s_setprio(1);                                             \
    _Pragma("unroll") for (int kk = 0; kk < 2; kk++)                           \
        _Pragma("unroll") for (int m2 = 0; m2 < 2; m2++)                       \
            _Pragma("unroll") for (int ni = 0; ni < 4; ni++)                   \
                acc[(MIBASE) + m2][ni] =                                       \
                    __builtin_amdgcn_mfma_f32_16x16x32_bf16(                   \
                        AP[m2][kk], b[ni][kk], acc[(MIBASE) + m2][ni], 0,0,0); \
    __builtin_amdgcn_s_setprio(0);                                             \
    __builtin_amdgcn_sched_barrier(0);                                         \
    __builtin_amdgcn_s_barrier();

    // prologue: tile0 fully, then tile1 fully (issue order matters for vmcnt)
#pragma unroll
    for (int j = 0; j < 4; j++) { STG_A(0, 0, j); STG_B(0, 0, j); }
#pragma unroll
    for (int j = 0; j < 4; j++) { STG_A(1, 1, j); STG_B(1, 1, j); }
    __builtin_amdgcn_sched_barrier(0);
    asm volatile("s_waitcnt vmcnt(8)" ::: "memory");   // tile0 landed
    __builtin_amdgcn_s_barrier();
    __builtin_amdgcn_sched_barrier(0);

    for (int t = 0; t < NT; ++t) {
        const int cur = t & 1;
        const __bf16* As_ = &lds[cur][0][0];
        const __bf16* Bs_ = &lds[cur][1][0];
        const bool pf = (t + 2 < NT);
        const int tn = t + 2;

        bf16x8 b[4][2], ap[2][2];

        // ---- phase 0: all B frags + A mi{0,1}; no staging ----
#pragma unroll
        for (int ni = 0; ni < 4; ni++)
#pragma unroll
            for (int kk = 0; kk < 2; kk++) {
                const int col  = wn * 64 + ni * 16 + l15;
                const int slot = (kk * 4 + l16) ^ (col & 7);
                b[ni][kk] = *(const bf16x8*)&Bs_[col * 64 + slot * 8];
            }
        LOAD_A(ap, 0);
        PHASE(ap, 0);

        // ---- phase 1: A mi{2,3}; stage B q0,q1 (B fully read in ph0) ----
        LOAD_A(ap, 2);
        if (pf) { STG_B(tn, cur, 0); STG_B(tn, cur, 1); }
        PHASE(ap, 2);

        // ---- phase 2: A mi{4,5}; stage B q2,q3 + A q0,q2 (read-done) ----
        LOAD_A(ap, 4);
        if (pf) { STG_B(tn, cur, 2); STG_B(tn, cur, 3);
                  STG_A(tn, cur, 0); STG_A(tn, cur, 2); }
        PHASE(ap, 4);

        // ---- phase 3: A mi{6,7}; no staging (A q1,q3 still being read) ----
        LOAD_A(ap, 6);
        PHASE(ap, 6);

        // ---- tile end: stage A q1,q3; counted wait for tile t+1 ----
        if (pf) { STG_A(tn, cur, 1); STG_A(tn, cur, 3); }
        __builtin_amdgcn_sched_barrier(0);
        if (pf) asm volatile("s_waitcnt vmcnt(8)" ::: "memory");
        else    asm volatile("s_waitcnt vmcnt(0)" ::: "memory");
        __builtin_amdgcn_s_barrier();
        __builtin_amdgcn_sched_barrier(0);
    }
#undef STG_A
#undef STG_B
#undef LOAD_A
#undef PHASE

    // epilogue: C/D layout col=lane&15, row=(lane>>4)*4+q
#pragma unroll
    for (int mi = 0; mi < 8; mi++) {
#pragma unroll
        for (int ni = 0; ni < 4; ni++) {
            const int col = c0 + wn * 64 + ni * 16 + l15;
            const int row = r0 + wm * 128 + mi * 16 + l16 * 4;
            if (col < DIM_MEM) {
#pragma unroll
                for (int q = 0; q < 4; q++)
                    C[(size_t)(row + q) * DIM_MEM + col] = acc[mi][ni][q];
            } else if (col < TOTAL_DIM) {
#pragma unroll
                for (int q = 0; q < 4; q++)
                    Cq[(size_t)(row + q) * DIM_Q + (col - DIM_MEM)] =
                        (__bf16)acc[mi][ni][q];
            }
        }
    }
}

// ================= GEMM2: 128^2 tile, 8 waves, dbuf + counted vmcnt =========
__global__ __launch_bounds__(512, 2) void gemm_mid(const __bf16* __restrict__ A,
                                                   const __bf16* __restrict__ Bt,
                                                   float* __restrict__ C,
                                                   int Ndim, int Kdim, int gx) {
    __shared__ __bf16 lds[2][2][128 * 64];   // 64 KiB

    const int tid  = threadIdx.x;
    const int w    = tid >> 6;              // 0..7
    const int lane = tid & 63;
    const int l15  = lane & 15;
    const int l16  = lane >> 4;
    const int wm   = w >> 1;                // 0..3 (M)
    const int wn   = w & 1;                 // 0..1 (N)

    const int nwg = gridDim.x;
    int lin = blockIdx.x;
    lin = (lin & 7) * (nwg >> 3) + (lin >> 3);
    const int bx = lin % gx, by = lin / gx;
    const int r0 = by * 128, c0 = bx * 128;

    const int srl   = lane >> 3;
    const int sslot = lane & 7;

    f32x4 acc[2][4] = {};
    const int NT = Kdim / 64;

#define STG4(T, BUF)                                                           \
    _Pragma("unroll") for (int j = 0; j < 2; j++) {                            \
        const int r_  = j * 64 + w * 8 + srl;                                  \
        const int so_ = sslot ^ (r_ & 7);                                      \
        gload_lds16(A + (size_t)(r0 + r_) * Kdim + (T) * 64 + so_ * 8,         \
                    &lds[BUF][0][(j * 64 + w * 8) * 64]);                      \
        gload_lds16(Bt + (size_t)(c0 + r_) * Kdim + (T) * 64 + so_ * 8,        \
                    &lds[BUF][1][(j * 64 + w * 8) * 64]);                      \
    }

    STG4(0, 0);
    STG4(1, 1);
    __builtin_amdgcn_sched_barrier(0);
    asm volatile("s_waitcnt vmcnt(4)" ::: "memory");
    __builtin_amdgcn_s_barrier();
    __builtin_amdgcn_sched_barrier(0);

    for (int t = 0; t < NT; ++t) {
        const int cur = t & 1;
        const __bf16* As_ = &lds[cur][0][0];
        const __bf16* Bs_ = &lds[cur][1][0];
        const bool pf = (t + 2 < NT);

        bf16x8 b[4][2], a[2][2];
#pragma unroll
        for (int ni = 0; ni < 4; ni++)
#pragma unroll
            for (int kk = 0; kk < 2; kk++) {
                const int col  = wn * 64 + ni * 16 + l15;
                const int slot = (kk * 4 + l16) ^ (col & 7);
                b[ni][kk] = *(const bf16x8*)&Bs_[col * 64 + slot * 8];
            }
#pragma unroll
        for (int mi = 0; mi < 2; mi++)
#pragma unroll
            for (int kk = 0; kk < 2; kk++) {
                const int row  = wm * 32 + mi * 16 + l15;
                const int slot = (kk * 4 + l16) ^ (row & 7);
                a[mi][kk] = *(const bf16x8*)&As_[row * 64 + slot * 8];
            }
        asm volatile("s_waitcnt lgkmcnt(0)" ::: "memory");
        __builtin_amdgcn_sched_barrier(0);
        __builtin_amdgcn_s_setprio(1);
#pragma unroll
        for (int kk = 0; kk < 2; kk++)
#pragma unroll
            for (int mi = 0; mi < 2; mi++)
#pragma unroll
                for (int ni = 0; ni < 4; ni++)
                    acc[mi][ni] = __builtin_amdgcn_mfma_f32_16x16x32_bf16(
                        a[mi][kk], b[ni][kk], acc[mi][ni], 0, 0, 0);
        __builtin_amdgcn_s_setprio(0);
        __builtin_amdgcn_sched_barrier(0);
        __builtin_amdgcn_s_barrier();          // reads done
        if (pf) STG4(t + 2, cur);
        __builtin_amdgcn_sched_barrier(0);
        if (pf) asm volatile("s_waitcnt vmcnt(4)" ::: "memory");
        else    asm volatile("s_waitcnt vmcnt(0)" ::: "memory");
        __builtin_amdgcn_s_barrier();
        __builtin_amdgcn_sched_barrier(0);
    }
#undef STG4

#pragma unroll
    for (int mi = 0; mi < 2; mi++) {
#pragma unroll
        for (int ni = 0; ni < 4; ni++) {
            const int col = c0 + wn * 64 + ni * 16 + l15;
            const int row = r0 + wm * 32 + mi * 16 + l16 * 4;
#pragma unroll
            for (int q = 0; q < 4; q++)
                C[(size_t)(row + q) * Ndim + col] = acc[mi][ni][q];
        }
    }
}

// ---------------- straight cast fp32 -> bf16 ----------------
__global__ __launch_bounds__(256) void cast_bf16(const float* __restrict__ in,
                                                 __bf16* __restrict__ out, int n4) {
    const int i = blockIdx.x * blockDim.x + threadIdx.x;
    if (i >= n4) return;
    const float4 v = ((const float4*)in)[i];
    bf16x4 o;
    o.x = (__bf16)v.x; o.y = (__bf16)v.y; o.z = (__bf16)v.z; o.w = (__bf16)v.w;
    ((bf16x4*)out)[i] = o;
}

// ---------------- transpose-cast: W[K,N] f32 -> Wt[Npad,K] bf16 ----------------
__global__ __launch_bounds__(256) void transpose_cast(const float* __restrict__ W,
                                                      __bf16* __restrict__ Wt,
                                                      int Kdim, int Ndim, int Npad) {
    __shared__ float tile[32][33];
    const int n0 = blockIdx.x * 32, k0 = blockIdx.y * 32;
    const int tx = threadIdx.x & 31, ty = threadIdx.x >> 5;
#pragma unroll
    for (int i = 0; i < 32; i += 8) {
        float v = 0.f;
        if (n0 + tx < Ndim) v = W[(size_t)(k0 + ty + i) * Ndim + n0 + tx];
        tile[ty + i][tx] = v;
    }
    __syncthreads();
#pragma unroll
    for (int i = 0; i < 32; i += 8) {
        const int n = n0 + ty + i;
        if (n < Npad) Wt[(size_t)n * Kdim + k0 + tx] = (__bf16)tile[tx][ty + i];
    }
}

// ---------------- depthwise causal conv + gate weights ----------------
__global__ __launch_bounds__(256) void conv_pw(const float* __restrict__ z_mem,
                                               const float* __restrict__ conv_k,
                                               const float* __restrict__ score_scale,
                                               const float* __restrict__ decay_slopes,
                                               const float* __restrict__ anchor_slopes,
                                               __bf16* __restrict__ k_val,
                                               float* __restrict__ p_w) {
    const int bl = blockIdx.x;
    const int l = bl & (L_SEQ - 1);
    const int b = bl >> 11;
    const int t = threadIdx.x;

    {
        const int c = 4 * t;
        float4 acc = {0.f, 0.f, 0.f, 0.f};
#pragma unroll
        for (int s = 0; s < KS; s++) {
            const int tl = l - (KS - 1) + s;
            if (tl >= 0) {
                const float4 ck = *(const float4*)&conv_k[s * DIM_MEM + c];
                const float4 zv = *(const float4*)&z_mem[((size_t)b * L_SEQ + tl) * DIM_MEM + c];
                acc.x = fmaf(ck.x, zv.x, acc.x);
                acc.y = fmaf(ck.y, zv.y, acc.y);
                acc.z = fmaf(ck.z, zv.z, acc.z);
                acc.w = fmaf(ck.w, zv.w, acc.w);
            }
        }
        bf16x4 o;
        o.x = (__bf16)acc.x; o.y = (__bf16)acc.y;
        o.z = (__bf16)acc.z; o.w = (__bf16)acc.w;
        *(bf16x4*)&k_val[(size_t)bl * DIM_K + c] = o;
    }

    if (t < 8) {
        const int c = DIM_MEM - K_TOT + 4 * t;
        float acc[4] = {0.f, 0.f, 0.f, 0.f};
#pragma unroll
        for (int s = 0; s < KS; s++) {
            const int tl = l - (KS - 1) + s;
            if (tl >= 0) {
                const float4 ck = *(const float4*)&conv_k[s * DIM_MEM + c];
                const float4 zv = *(const float4*)&z_mem[((size_t)b * L_SEQ + tl) * DIM_MEM + c];
                acc[0] = fmaf(ck.x, zv.x, acc[0]);
                acc[1] = fmaf(ck.y, zv.y, acc[1]);
                acc[2] = fmaf(ck.z, zv.z, acc[2]);
                acc[3] = fmaf(ck.w, zv.w, acc[3]);
            }
        }
#pragma unroll
        for (int j = 0; j < 4; j++) {
            const int k = 4 * t + j;
            const float lp = fminf(fmaxf(score_scale[k] * acc[j], -20.f), 20.f);
            float lt;
            if (k < N_DECAY) {
                const float sd = log1pf(__expf(decay_slopes[k]));
                lt = -sd * (float)(L_SEQ - 1 - l);
            } else {
                const float sa = log1pf(__expf(anchor_slopes[k - N_DECAY]));
                lt = -sa * (float)l;
            }
            p_w[(size_t)bl * K_TOT + k] = __expf(lp + lt);
        }
    }
}

// ---------------- phase 1: per-chunk totals (rotation over m) ----------------
__global__ __launch_bounds__(256) void chunk_sums(const __bf16* __restrict__ k_val,
                                                  const float* __restrict__ p_w,
                                                  const float* __restrict__ theta,
                                                  float* __restrict__ csum,
                                                  float* __restrict__ cden) {
    const int idx = blockIdx.x;
    const int c = idx & (NCHUNK - 1);
    const int bkg = idx / NCHUNK;
    const int kg = bkg & (KG_CNT - 1);
    const int b = bkg / KG_CNT;
    const int t = threadIdx.x;
    const int kl = t >> 5;
    const int h = t & 31;
    const int k = kg * 8 + kl;
    const int bk = b * K_TOT + k;

    const float A0 = theta[(k * H_DIM + h) * M_DIM + 0];
    const float Dt = theta[(k * H_DIM + h) * M_DIM + 1] - A0;

    float nre[M_DIM] = {}, nim[M_DIM] = {};
    float den = 0.f;
    const int l0 = c * CHUNK_L;
#pragma unroll 2
    for (int i = 0; i < CHUNK_L; i++) {
        const size_t bl = (size_t)b * L_SEQ + (l0 + i);
        const float p  = p_w[bl * K_TOT + k];
        const float kv = (float)k_val[bl * DIM_K + k * H_DIM + h];
        float cc = __cosf(kv * A0), ss = __sinf(kv * A0);
        const float cd = __cosf(kv * Dt), sd = __sinf(kv * Dt);
#pragma unroll
        for (int m = 0; m < M_DIM; m++) {
            nre[m] = fmaf(p, cc, nre[m]);
            nim[m] = fmaf(p, ss, nim[m]);
            const float c2 = fmaf(cc, cd, -(ss * sd));
            ss = fmaf(ss, cd, cc * sd);
            cc = c2;
        }
        den += p;
    }

    float* base = &csum[(((size_t)bk * NCHUNK + c) * 256 + h * M_DIM) * 2];
#pragma unroll
    for (int j = 0; j < 4; j++) {
        f32x4 v = { nre[2 * j], nim[2 * j], nre[2 * j + 1], nim[2 * j + 1] };
        ((f32x4*)base)[j] = v;
    }
    if (h == 0) cden[bk * NCHUNK + c] = den;
}

// ---------------- phase 2: exclusive prefix over chunks ----------------
__global__ __launch_bounds__(256) void chunk_prefix(float* __restrict__ csum,
                                                    float* __restrict__ cden) {
    const int bk = blockIdx.x;
    const int t = threadIdx.x;

    if (t < 64) {
        const float orig = cden[bk * NCHUNK + t];
        float v = orig;
#pragma unroll
        for (int d = 1; d < 64; d <<= 1) {
            const float u = __shfl_up(v, d);
            if (t >= d) v += u;
        }
        cden[bk * NCHUNK + t] = v - orig;
    }

    float run_re = 0.f, run_im = 0.f;
    for (int c = 0; c < NCHUNK; c++) {
        float2* p = (float2*)&csum[(((size_t)bk * NCHUNK + c) * 256 + t) * 2];
        const float2 v = *p;
        *p = make_float2(run_re, run_im);
        run_re += v.x;
        run_im += v.y;
    }
}

// ---------------- phase 3: replay + output epilogue ----------------
__global__ __launch_bounds__(256) void scan_out(const __bf16* __restrict__ q_b,
                                                const __bf16* __restrict__ k_val,
                                                const float* __restrict__ p_w,
                                                const float* __restrict__ theta,
                                                const float* __restrict__ csum,
                                                const float* __restrict__ cden,
                                                const float* __restrict__ W_re,
                                                const float* __restrict__ W_im,
                                                const float* __restrict__ norm_scale,
                                                __bf16* __restrict__ y) {
    const int idx = blockIdx.x;
    const int c = idx & (NCHUNK - 1);
    const int bkg = idx / NCHUNK;
    const int kg = bkg & (KG_CNT - 1);
    const int b = bkg / KG_CNT;
    const int t = threadIdx.x;
    const int kl = t >> 5;
    const int h = t & 31;
    const int k = kg * 8 + kl;
    const int bk = b * K_TOT + k;

    const float A0 = theta[(k * H_DIM + h) * M_DIM + 0];
    const float Dt = theta[(k * H_DIM + h) * M_DIM + 1] - A0;

    float nre[M_DIM], nim[M_DIM];
    {
        const float* base = &csum[(((size_t)bk * NCHUNK + c) * 256 + h * M_DIM) * 2];
#pragma unroll
        for (int j = 0; j < 4; j++) {
            const f32x4 v = ((const f32x4*)base)[j];
            nre[2 * j] = v.x; nim[2 * j] = v.y;
            nre[2 * j + 1] = v.z; nim[2 * j + 1] = v.w;
        }
    }
    float den = cden[bk * NCHUNK + c];

    const float wsc_re = norm_scale[h] * W_re[h * H_DIM + h];
    const float wsc_im = norm_scale[H_DIM + h] * W_im[h * H_DIM + h];

    const int l0 = c * CHUNK_L;
    for (int i = 0; i < CHUNK_L; i++) {
        const size_t bl = (size_t)b * L_SEQ + (l0 + i);
        const float p  = p_w[bl * K_TOT + k];
        const float kv = (float)k_val[bl * DIM_K + k * H_DIM + h];

        const __bf16* qp = &q_b[bl * DIM_Q + (size_t)(kg * H_DIM + h) * 16];
        const bf16x8 q0 = *(const bf16x8*)qp;
        const bf16x8 q1 = *(const bf16x8*)(qp + 8);

        float cc = __cosf(kv * A0), ss = __sinf(kv * A0);
        const float cd = __cosf(kv * Dt), sd = __sinf(kv * Dt);

        float ore = 0.f, oim = 0.f;
#pragma unroll
        for (int m = 0; m < M_DIM; m++) {
            nre[m] = fmaf(p, cc, nre[m]);
            nim[m] = fmaf(p, ss, nim[m]);
            const float qr = (m < 4) ? (float)q0[2 * (m & 3)]     : (float)q1[2 * (m & 3)];
            const float qi = (m < 4) ? (float)q0[2 * (m & 3) + 1] : (float)q1[2 * (m & 3) + 1];
            ore = fmaf(nre[m], qr, fmaf(nim[m], qi, ore));
            oim = fmaf(nim[m], qr, fmaf(-nre[m], qi, oim));
            const float c2 = fmaf(cc, cd, -(ss * sd));
            ss = fmaf(ss, cd, cc * sd);
            cc = c2;
        }
        den += p;
        const float inv = __builtin_amdgcn_rcpf(fmaxf(den, 1e-4f));

        const float v = (ore * wsc_re + oim * wsc_im) * inv;
        const float yv = v * __builtin_amdgcn_rcpf(1.0f + __expf(-v));
        y[bl * DIM_K + k * H_DIM + h] = (__bf16)yv;
    }
}

// ---------------- launch ----------------
extern "C" void kernel_launch(void* const* d_in, const int* in_sizes, int n_in,
                              void* d_out, int out_size, void* d_ws, size_t ws_size,
                              hipStream_t stream) {
    const float* x            = (const float*)d_in[0];
    const float* W_in         = (const float*)d_in[1];
    const float* conv_k       = (const float*)d_in[2];
    const float* theta        = (const float*)d_in[3];
    const float* decay_slopes = (const float*)d_in[4];
    const float* anchor_slopes= (const float*)d_in[5];
    const float* score_scale  = (const float*)d_in[6];
    const float* W_re         = (const float*)d_in[7];
    const float* W_im         = (const float*)d_in[8];
    const float* norm_scale   = (const float*)d_in[9];
    const float* W_out        = (const float*)d_in[10];
    float* out = (float*)d_out;

    float* ws = (float*)d_ws;
    size_t off = 0;
    float* z_mem  = ws + off; off += (size_t)BL_TOT * DIM_MEM;
    float* p_w    = ws + off; off += (size_t)BL_TOT * K_TOT;
    float* csum   = ws + off; off += (size_t)B_SZ * K_TOT * NCHUNK * 256 * 2;
    float* cden   = ws + off; off += (size_t)B_SZ * K_TOT * NCHUNK;
    __bf16* k_val   = (__bf16*)(ws + off); off += (size_t)BL_TOT * DIM_K / 2;
    __bf16* x_b     = (__bf16*)(ws + off); off += (size_t)BL_TOT * D_MODEL / 2;
    __bf16* W_in_T  = (__bf16*)(ws + off); off += (size_t)NPAD_IN * D_MODEL / 2;
    __bf16* W_out_T = (__bf16*)(ws + off); off += (size_t)D_MODEL * D_MODEL / 2;
    __bf16* y_b     = (__bf16*)(ws + off); off += (size_t)BL_TOT * DIM_K / 2;
    __bf16* q_b     = (__bf16*)(ws + off); off += (size_t)BL_TOT * DIM_Q / 2;

    cast_bf16<<<(BL_TOT * D_MODEL / 4 + 255) / 256, 256, 0, stream>>>(
        x, x_b, BL_TOT * D_MODEL / 4);
    {
        dim3 g(NPAD_IN / 32, D_MODEL / 32);
        transpose_cast<<<g, 256, 0, stream>>>(W_in, W_in_T, D_MODEL, TOTAL_DIM, NPAD_IN);
    }
    {
        dim3 g(D_MODEL / 32, D_MODEL / 32);
        transpose_cast<<<g, 256, 0, stream>>>(W_out, W_out_T, D_MODEL, D_MODEL, D_MODEL);
    }

    // 1) z = x @ W_in (4-phase deep pipeline, split epilogue)
    gemm_big<<<(NPAD_IN / 256) * (BL_TOT / 256), 512, 0, stream>>>(
        x_b, W_in_T, z_mem, q_b, D_MODEL, NPAD_IN / 256);

    // 2) depthwise conv + p_w
    conv_pw<<<BL_TOT, 256, 0, stream>>>(z_mem, conv_k, score_scale, decay_slopes,
                                        anchor_slopes, k_val, p_w);
    // 3) blocked scan
    chunk_sums<<<B_SZ * KG_CNT * NCHUNK, 256, 0, stream>>>(k_val, p_w, theta, csum, cden);
    chunk_prefix<<<B_SZ * K_TOT, 256, 0, stream>>>(csum, cden);
    scan_out<<<B_SZ * KG_CNT * NCHUNK, 256, 0, stream>>>(q_b, k_val, p_w, theta, csum,
                                                         cden, W_re, W_im, norm_scale, y_b);
    // 4) out = y @ W_out (128^2, 8-wave pipelined)
    gemm_mid<<<(D_MODEL / 128) * (BL_TOT / 128), 512, 0, stream>>>(
        y_b, W_out_T, out, D_MODEL, D_MODEL, D_MODEL / 128);
}